// Round 24
// baseline (1119.514 us; speedup 1.0000x reference)
//
#include <hip/hip_runtime.h>
#include <hip/hip_bf16.h>
#include <string.h>

#define NNODES 50000
#define TSTEPS 8
#define NEDGES 800000
#define VVOCAB 1000
#define DDIM 32
#define HDIM 128
#define G0DIM 64
#define H3 384
#define NSB 4          // src blocks: key = dst*NSB + src/SRCBLK
#define SRCBLK 12500
#define NKEY (NNODES * NSB)      // 200000 keys per timestep
#define NBLK 256                 // edge blocks per timestep for the sort
#define EPB 3125                 // edges per block (256*3125 = 800000 exactly)
#define COARSE 391               // coarse bins = key>>9 (max key 199999 -> 390)
#define FINEN 512                // fine keys per coarse bin (key & 511)
#define NSCN (COARSE * NBLK)     // 100096
#define NCHK2 196                // ceil(NSCN/512)
#define STAGE_CAP 4096           // LDS staging capacity for fine_sort bins

typedef _Float16 v8h __attribute__((ext_vector_type(8)));
typedef float v4f __attribute__((ext_vector_type(4)));

__device__ __forceinline__ float w_decode(unsigned int packed) {
  unsigned short wb = (unsigned short)(packed >> 16);
  _Float16 h;
  __builtin_memcpy(&h, &wb, 2);
  return (float)h;
}

// ---- fast transcendentals (v_exp_f32 + v_rcp_f32), safe for fp16-precision outputs ------
__device__ __forceinline__ float fsigmoid(float v) {
  return __builtin_amdgcn_rcpf(1.f + __expf(-v));
}
__device__ __forceinline__ float ftanh(float x) {
  float xc = fminf(fmaxf(x, -15.f), 15.f);
  float e2 = __expf(2.f * xc);
  return (e2 - 1.f) * __builtin_amdgcn_rcpf(e2 + 1.f);
}

// ============== Atomic-free two-level counting sort (CSR build) ===========================

// A1: per-block LDS histogram over coarse bins -> bh[t][coarse*NBLK + block]
__global__ __launch_bounds__(512) void coarse_hist(const int* __restrict__ edges,
                                                   int* __restrict__ bh) {
  __shared__ int hist[COARSE];
  int t = blockIdx.y, b = blockIdx.x, tid = threadIdx.x;
  for (int i = tid; i < COARSE; i += 512) hist[i] = 0;
  __syncthreads();
  const int* srcp = edges + (size_t)t * 2 * NEDGES + (size_t)b * EPB;
  const int* dstp = srcp + NEDGES;
  for (int i = tid; i < EPB; i += 512) {
    int key = dstp[i] * NSB + srcp[i] / SRCBLK;
    atomicAdd(&hist[key >> 9], 1);
  }
  __syncthreads();
  for (int i = tid; i < COARSE; i += 512) bh[(size_t)t * NSCN + i * NBLK + b] = hist[i];
}

// scan of bh[t][0..NSCN) -> bscan (exclusive), hierarchical
__global__ __launch_bounds__(256) void scan_c1(const int* __restrict__ bh,
                                               int* __restrict__ csum) {
  int bid = blockIdx.x;  // t*NCHK2 + c
  int t = bid / NCHK2, c = bid % NCHK2;
  int tid = threadIdx.x;
  int s = 0;
#pragma unroll
  for (int i = 0; i < 2; ++i) {
    int n = c * 512 + tid + i * 256;
    if (n < NSCN) s += bh[(size_t)t * NSCN + n];
  }
#pragma unroll
  for (int off = 32; off > 0; off >>= 1) s += __shfl_down(s, off, 64);
  __shared__ int wsum[4];
  if ((tid & 63) == 0) wsum[tid >> 6] = s;
  __syncthreads();
  if (tid == 0) csum[bid] = wsum[0] + wsum[1] + wsum[2] + wsum[3];
}

__global__ __launch_bounds__(512) void scan_c2(const int* __restrict__ csum,
                                               int* __restrict__ cbase) {
  int t = blockIdx.x;
  int tid = threadIdx.x;
  __shared__ int buf[512];
  int own = (tid < NCHK2) ? csum[t * NCHK2 + tid] : 0;
  buf[tid] = own;
  __syncthreads();
  for (int d = 1; d < 512; d <<= 1) {
    int v = (tid >= d) ? buf[tid - d] : 0;
    __syncthreads();
    buf[tid] += v;
    __syncthreads();
  }
  if (tid < NCHK2) cbase[t * NCHK2 + tid] = buf[tid] - own;
}

__global__ __launch_bounds__(512) void scan_c3(const int* __restrict__ bh,
                                               const int* __restrict__ cbase,
                                               int* __restrict__ bscan) {
  int bid = blockIdx.x;
  int t = bid / NCHK2, c = bid % NCHK2;
  int tid = threadIdx.x;
  int n = c * 512 + tid;
  int d = (n < NSCN) ? bh[(size_t)t * NSCN + n] : 0;
  __shared__ int buf[512];
  buf[tid] = d;
  __syncthreads();
  for (int s = 1; s < 512; s <<= 1) {
    int v = (tid >= s) ? buf[tid - s] : 0;
    __syncthreads();
    buf[tid] += v;
    __syncthreads();
  }
  if (n < NSCN) bscan[(size_t)t * NSCN + n] = cbase[bid] + buf[tid] - d;
}

// A3: LDS-staged scatter with recorded bin ids. Block sorts its 3125 edges by coarse bin
// in LDS (binof[] remembers each slot's bin), then sweeps out linearly with a single
// LDS lookup per element (no binary search).
__global__ __launch_bounds__(512) void coarse_scatter(
    const int* __restrict__ edges, const float* __restrict__ weights,
    const int* __restrict__ bscan, int2* __restrict__ tmp) {
  __shared__ int hist[COARSE], lstart[COARSE], cur[COARSE], scanb[COARSE];
  __shared__ int2 stage[EPB];                 // 25KB
  __shared__ unsigned short binof[EPB];       // 6.25KB
  int t = blockIdx.y, b = blockIdx.x, tid = threadIdx.x;
  for (int i = tid; i < COARSE; i += 512) hist[i] = 0;
  __syncthreads();
  const int* srcp = edges + (size_t)t * 2 * NEDGES + (size_t)b * EPB;
  const int* dstp = srcp + NEDGES;
  const float* wp = weights + (size_t)t * NEDGES + (size_t)b * EPB;
  for (int i = tid; i < EPB; i += 512) {
    int key = dstp[i] * NSB + srcp[i] / SRCBLK;
    atomicAdd(&hist[key >> 9], 1);
  }
  __syncthreads();
  if (tid < COARSE) scanb[tid] = hist[tid];
  __syncthreads();
  for (int d = 1; d < COARSE; d <<= 1) {
    int v = 0;
    if (tid < COARSE && tid >= d) v = scanb[tid - d];
    __syncthreads();
    if (tid < COARSE) scanb[tid] += v;
    __syncthreads();
  }
  if (tid < COARSE) {
    int ls = scanb[tid] - hist[tid];
    lstart[tid] = ls;
    cur[tid] = ls;
  }
  __syncthreads();
  for (int i = tid; i < EPB; i += 512) {
    int src = srcp[i];
    int key = dstp[i] * NSB + src / SRCBLK;
    int coarse = key >> 9, fine = key & 511;
    int lpos = atomicAdd(&cur[coarse], 1);  // LDS atomic
    int2 pk;
    pk.x = src | (fine << 16);
    pk.y = __float_as_int(wp[i]);
    stage[lpos] = pk;
    binof[lpos] = (unsigned short)coarse;
  }
  __syncthreads();
  for (int j = tid; j < EPB; j += 512) {
    int lo = binof[j];
    int gpos = bscan[(size_t)t * NSCN + lo * NBLK + b] + (j - lstart[lo]);
    tmp[(size_t)t * NEDGES + gpos] = stage[j];
  }
}

// B: per (t,coarse) bin: LDS counting sort over 512 fine keys -> packed 4B csr + offs.
__global__ __launch_bounds__(512) void fine_sort(
    const int* __restrict__ bscan, const int2* __restrict__ tmp,
    unsigned int* __restrict__ csr, int* __restrict__ offs) {
  __shared__ int fhist[FINEN], fbase[FINEN], fcur[FINEN], buf[FINEN];
  __shared__ unsigned int stage[STAGE_CAP];
  int t = blockIdx.y, coarse = blockIdx.x, tid = threadIdx.x;
  int cb0 = bscan[(size_t)t * NSCN + coarse * NBLK];
  int cb1 = (coarse == COARSE - 1) ? NEDGES : bscan[(size_t)t * NSCN + (coarse + 1) * NBLK];
  int size = cb1 - cb0;
  fhist[tid] = 0;
  fcur[tid] = 0;
  __syncthreads();
  const int2* bin = tmp + (size_t)t * NEDGES + cb0;
  for (int i = tid; i < size; i += 512) {
    int fine = (bin[i].x >> 16) & 511;
    atomicAdd(&fhist[fine], 1);
  }
  __syncthreads();
  buf[tid] = fhist[tid];
  __syncthreads();
  for (int d = 1; d < FINEN; d <<= 1) {
    int v = (tid >= d) ? buf[tid - d] : 0;
    __syncthreads();
    buf[tid] += v;
    __syncthreads();
  }
  fbase[tid] = buf[tid] - fhist[tid];
  int key = coarse * FINEN + tid;
  if (key < NKEY) offs[(size_t)t * (NKEY + 1) + key] = cb0 + fbase[tid];
  if (coarse == COARSE - 1 && tid == 0) offs[(size_t)t * (NKEY + 1) + NKEY] = NEDGES;
  __syncthreads();
  unsigned int* outp = csr + (size_t)t * NEDGES + cb0;
  if (size <= STAGE_CAP) {
    for (int i = tid; i < size; i += 512) {
      int2 p = bin[i];
      int fine = (p.x >> 16) & 511;
      int lr = atomicAdd(&fcur[fine], 1);  // LDS atomic
      _Float16 wh = (_Float16)__int_as_float(p.y);
      unsigned short wb;
      __builtin_memcpy(&wb, &wh, 2);
      stage[fbase[fine] + lr] = (unsigned int)(p.x & 0xFFFF) | ((unsigned int)wb << 16);
    }
    __syncthreads();
    for (int i = tid; i < size; i += 512) outp[i] = stage[i];
  } else {
    for (int i = tid; i < size; i += 512) {
      int2 p = bin[i];
      int fine = (p.x >> 16) & 511;
      int lr = atomicAdd(&fcur[fine], 1);  // LDS atomic
      _Float16 wh = (_Float16)__int_as_float(p.y);
      unsigned short wb;
      __builtin_memcpy(&wb, &wh, 2);
      outp[fbase[fine] + lr] = (unsigned int)(p.x & 0xFFFF) | ((unsigned int)wb << 16);
    }
  }
}

// ============== Gathers (4B packed csr entries) ===========================================

template <int D>
__global__ __launch_bounds__(256) void gather_merged(
    const int* __restrict__ off, const unsigned int* __restrict__ csr,
    const _Float16* __restrict__ x, _Float16* __restrict__ m) {
  const int LPN = D / 8;
  int n = blockIdx.x * (256 / LPN) + threadIdx.x / LPN;
  int l = threadIdx.x % LPN;
  if (n >= NNODES) return;
  int s0 = off[n * NSB], s1 = off[(n + 1) * NSB];
  float a0[8], a1[8];
#pragma unroll
  for (int i = 0; i < 8; ++i) { a0[i] = 0.f; a1[i] = 0.f; }
  int e = s0;
  for (; e + 1 < s1; e += 2) {
    unsigned int eA = csr[e], eB = csr[e + 1];
    v8h xA = *(const v8h*)&x[(size_t)(eA & 0xFFFF) * D + l * 8];
    v8h xB = *(const v8h*)&x[(size_t)(eB & 0xFFFF) * D + l * 8];
    float wA = w_decode(eA), wB = w_decode(eB);
#pragma unroll
    for (int i = 0; i < 8; ++i) {
      a0[i] += wA * (float)xA[i];
      a1[i] += wB * (float)xB[i];
    }
  }
  if (e < s1) {
    unsigned int eA = csr[e];
    v8h xA = *(const v8h*)&x[(size_t)(eA & 0xFFFF) * D + l * 8];
    float wA = w_decode(eA);
#pragma unroll
    for (int i = 0; i < 8; ++i) a0[i] += wA * (float)xA[i];
  }
  v8h r;
#pragma unroll
  for (int i = 0; i < 8; ++i) r[i] = (_Float16)(a0[i] + a1[i]);
  *(v8h*)&m[(size_t)n * D + l * 8] = r;
}

// ============== Dense kernels =============================================================

__global__ __launch_bounds__(384) void fuse_w(
    const float* __restrict__ gW2, const float* __restrict__ Wx, float* __restrict__ Wf) {
  int t = blockIdx.x >> 7;
  int k = blockIdx.x & 127;
  int j = threadIdx.x;
  __shared__ float row[HDIM];
  if (j < HDIM) row[j] = gW2[((size_t)t * HDIM + k) * HDIM + j];
  __syncthreads();
  float acc = 0.f;
#pragma unroll 8
  for (int c = 0; c < HDIM; ++c) acc += row[c] * Wx[c * H3 + j];
  Wf[((size_t)t * HDIM + k) * H3 + j] = acc;
}

__global__ __launch_bounds__(384) void fuse_b(
    const float* __restrict__ gb2, const float* __restrict__ Wx,
    const float* __restrict__ bx, float* __restrict__ bf) {
  int t = blockIdx.x;
  int j = threadIdx.x;
  __shared__ float row[HDIM];
  if (j < HDIM) row[j] = gb2[t * HDIM + j];
  __syncthreads();
  float acc = bx[j];
#pragma unroll 8
  for (int c = 0; c < HDIM; ++c) acc += row[c] * Wx[c * H3 + j];
  bf[t * H3 + j] = acc;
}

// pack combined fp16 weights in MFMA-lane-coalesced layout:
// Bp[t][ks(8)][cg(32)][lr(4)][lj(16)] of v8h, where col = cg*16+lj, k = ks*32 + lr*8 + i.
__global__ __launch_bounds__(256) void pack_wcomb(
    const float* __restrict__ Wf32, const float* __restrict__ Wh,
    _Float16* __restrict__ Bp) {
  int t = blockIdx.x >> 9;
  int col = blockIdx.x & 511;
  int k = threadIdx.x;  // 0..255
  float v;
  if (col < 384) {
    if (k < 128) v = Wf32[((size_t)t * HDIM + k) * H3 + col];
    else v = (col < 256) ? Wh[(size_t)(k - 128) * H3 + col] : 0.f;
  } else {
    v = (k < 128) ? 0.f : Wh[(size_t)(k - 128) * H3 + (col - 128)];
  }
  int cg = col >> 4, lj = col & 15;
  int ks = k >> 5, rem = k & 31, lr = rem >> 3, ki = rem & 7;
  size_t idx = ((((((size_t)t * 8 + ks) * 32 + cg) * 4 + lr) * 16 + lj) * 8) + ki;
  Bp[idx] = (_Float16)v;
}

__global__ __launch_bounds__(512) void pack_bcomb(
    const float* __restrict__ bfb, const float* __restrict__ bh,
    float* __restrict__ bcomb) {
  int t = blockIdx.x;
  int c = threadIdx.x;
  float v;
  if (c < 256) v = bfb[t * H3 + c] + bh[c];
  else if (c < 384) v = bfb[t * H3 + c];
  else v = bh[c - 128];
  bcomb[t * 512 + c] = v;
}

// static encoder + attn init: acch (fp16) = se, sden = 1, mxv = logit
__global__ __launch_bounds__(128) void static_encode_attn_init(
    const float* __restrict__ dense, const int* __restrict__ sparse,
    const float* __restrict__ emb,
    const float* __restrict__ Ws, const float* __restrict__ bs,
    const float* __restrict__ Waw, const float* __restrict__ baw,
    _Float16* __restrict__ acch, float* __restrict__ s, float* __restrict__ mx) {
  int n = blockIdx.x;
  int j = threadIdx.x;
  __shared__ float xs[G0DIM];
  if (j < G0DIM) {
    float v;
    if (j < 16) {
      v = emb[sparse[n * 2 + 0] * 16 + j];
    } else if (j < 32) {
      v = emb[VVOCAB * 16 + sparse[n * 2 + 1] * 16 + (j - 16)];
    } else {
      v = dense[n * DDIM + (j - 32)];
    }
    xs[j] = v;
  }
  __syncthreads();
  float a = bs[j];
#pragma unroll 16
  for (int k = 0; k < G0DIM; ++k) a += xs[k] * Ws[k * HDIM + j];
  a = fmaxf(a, 0.f);
  float v = ftanh(a) * Waw[j];
  __shared__ float red[2];
  int lane = j & 63, wid = j >> 6;
#pragma unroll
  for (int off = 32; off > 0; off >>= 1) v += __shfl_down(v, off, 64);
  if (lane == 0) red[wid] = v;
  __syncthreads();
  acch[(size_t)n * HDIM + j] = (_Float16)a;
  if (j == 0) {
    s[n] = 1.f;
    mx[n] = red[0] + red[1] + baw[0];
  }
}

__global__ __launch_bounds__(256) void dynx_gather_h(
    const float* __restrict__ dense_t, const int* __restrict__ sparse_t,
    const float* __restrict__ emb, _Float16* __restrict__ xout) {
  int idx = blockIdx.x * 256 + threadIdx.x;  // over N*8
  int n = idx >> 3, k8 = idx & 7;
  if (n >= NNODES) return;
  const float* src;
  if (k8 < 2)
    src = &emb[sparse_t[n * 2 + 0] * 16 + k8 * 8];
  else if (k8 < 4)
    src = &emb[VVOCAB * 16 + sparse_t[n * 2 + 1] * 16 + (k8 - 2) * 8];
  else
    src = &dense_t[n * DDIM + (k8 - 4) * 8];
  float4 f0 = *(const float4*)src;
  float4 f1 = *(const float4*)(src + 4);
  v8h v = {(_Float16)f0.x, (_Float16)f0.y, (_Float16)f0.z, (_Float16)f0.w,
           (_Float16)f1.x, (_Float16)f1.y, (_Float16)f1.z, (_Float16)f1.w};
  *(v8h*)&xout[(size_t)n * G0DIM + k8 * 8] = v;
}

__global__ __launch_bounds__(64) void rowmm64(
    const _Float16* __restrict__ x, const float* __restrict__ W,
    const float* __restrict__ b, _Float16* __restrict__ y) {
  const int NB = 8;
  int n0 = blockIdx.x * NB;
  int j = threadIdx.x;
  __shared__ float xT[G0DIM][12];
#pragma unroll
  for (int q = 0; q < NB; ++q) xT[j][q] = (float)x[(size_t)(n0 + q) * G0DIM + j];
  __syncthreads();
  float acc0[NB], acc1[NB];
#pragma unroll
  for (int q = 0; q < NB; ++q) { acc0[q] = 0.f; acc1[q] = 0.f; }
#pragma unroll 4
  for (int k = 0; k < G0DIM; ++k) {
    float4 a = *(const float4*)&xT[k][0];
    float4 c = *(const float4*)&xT[k][4];
    float w0 = W[(size_t)k * HDIM + j];
    float w1 = W[(size_t)k * HDIM + j + 64];
    acc0[0] += a.x * w0; acc0[1] += a.y * w0; acc0[2] += a.z * w0; acc0[3] += a.w * w0;
    acc0[4] += c.x * w0; acc0[5] += c.y * w0; acc0[6] += c.z * w0; acc0[7] += c.w * w0;
    acc1[0] += a.x * w1; acc1[1] += a.y * w1; acc1[2] += a.z * w1; acc1[3] += a.w * w1;
    acc1[4] += c.x * w1; acc1[5] += c.y * w1; acc1[6] += c.z * w1; acc1[7] += c.w * w1;
  }
  float b0 = b[j], b1 = b[j + 64];
#pragma unroll
  for (int q = 0; q < NB; ++q) {
    y[(size_t)(n0 + q) * HDIM + j] = (_Float16)fmaxf(acc0[q] + b0, 0.f);
    y[(size_t)(n0 + q) * HDIM + j + 64] = (_Float16)fmaxf(acc1[q] + b1, 0.f);
  }
}

// MFMA GRU + attention. Coalesced B layout; fp16 h_lds; fast transcendentals.
__global__ __launch_bounds__(256) void gru_mfma(
    const _Float16* __restrict__ Xh, const _Float16* __restrict__ Hp,
    const _Float16* __restrict__ Bt, const float* __restrict__ bcomb,
    const float* __restrict__ Waw, const float* __restrict__ baw,
    _Float16* __restrict__ hout, _Float16* __restrict__ acch,
    float* __restrict__ outf, float* __restrict__ sden, float* __restrict__ mxv,
    int last) {
  const int AST = 264;
  __shared__ _Float16 A_lds[32 * AST];
  __shared__ _Float16 h_lds[32 * 132];
  __shared__ float lg[32], facs[32], ps[32], sdn[32];
  int tid = threadIdx.x;
  int w = tid >> 6, lane = tid & 63;
  int n0 = blockIdx.x * 32;

#pragma unroll
  for (int i = 0; i < 4; ++i) {
    int cid = tid + i * 256;
    int row = cid >> 5, ch = cid & 31;
    int n = n0 + row;
    v8h v = {(_Float16)0, (_Float16)0, (_Float16)0, (_Float16)0,
             (_Float16)0, (_Float16)0, (_Float16)0, (_Float16)0};
    if (n < NNODES) {
      if (ch < 16) v = *(const v8h*)&Xh[(size_t)n * HDIM + ch * 8];
      else if (Hp) v = *(const v8h*)&Hp[(size_t)n * HDIM + (ch - 16) * 8];
    }
    *(v8h*)&A_lds[row * AST + ch * 8] = v;
  }
  __syncthreads();

  int lj = lane & 15, lr = lane >> 4;
  const v8h* Bp = (const v8h*)Bt;  // [ks][cg][lr][lj] fragments, lane-coalesced
  v4f accf[2][8];
#pragma unroll
  for (int m = 0; m < 2; ++m)
#pragma unroll
    for (int f = 0; f < 8; ++f) accf[m][f] = (v4f){0.f, 0.f, 0.f, 0.f};

  for (int ks = 0; ks < 8; ++ks) {
    v8h a0 = *(const v8h*)&A_lds[lj * AST + ks * 32 + lr * 8];
    v8h a1 = *(const v8h*)&A_lds[(16 + lj) * AST + ks * 32 + lr * 8];
#pragma unroll
    for (int g = 0; g < 4; ++g)
#pragma unroll
      for (int p = 0; p < 2; ++p) {
        int cg = g * 8 + w * 2 + p;
        v8h b = Bp[((ks * 32 + cg) * 4 + lr) * 16 + lj];
        accf[0][g * 2 + p] =
            __builtin_amdgcn_mfma_f32_16x16x32_f16(a0, b, accf[0][g * 2 + p], 0, 0, 0);
        accf[1][g * 2 + p] =
            __builtin_amdgcn_mfma_f32_16x16x32_f16(a1, b, accf[1][g * 2 + p], 0, 0, 0);
      }
  }

#pragma unroll
  for (int p = 0; p < 2; ++p) {
    int j = (w * 2 + p) * 16 + lj;
    float br = bcomb[j], bz = bcomb[128 + j], bxn = bcomb[256 + j], bhn = bcomb[384 + j];
#pragma unroll
    for (int m = 0; m < 2; ++m)
#pragma unroll
      for (int reg = 0; reg < 4; ++reg) {
        int row = m * 16 + lr * 4 + reg;
        float r = fsigmoid(accf[m][0 + p][reg] + br);
        float z = fsigmoid(accf[m][2 + p][reg] + bz);
        float hp = (float)A_lds[row * AST + 128 + j];
        float nc = ftanh(accf[m][4 + p][reg] + bxn + r * (accf[m][6 + p][reg] + bhn));
        h_lds[row * 132 + j] = (_Float16)((1.f - z) * nc + z * hp);
      }
  }
  __syncthreads();

  float waw0 = Waw[lane], waw1 = Waw[lane + 64];
#pragma unroll
  for (int q = 0; q < 8; ++q) {
    int row = w * 8 + q;
    float v = ftanh((float)h_lds[row * 132 + lane]) * waw0 +
              ftanh((float)h_lds[row * 132 + lane + 64]) * waw1;
#pragma unroll
    for (int off = 32; off > 0; off >>= 1) v += __shfl_down(v, off, 64);
    if (lane == 0) lg[row] = v;
  }
  __syncthreads();
  if (tid < 32) {
    int n = n0 + tid;
    if (n < NNODES) {
      float l = lg[tid] + baw[0];
      float m = mxv[n];
      float mnew = fmaxf(m, l);
      float fac = __expf(m - mnew);
      float pp = __expf(l - mnew);
      facs[tid] = fac;
      ps[tid] = pp;
      float snew = sden[n] * fac + pp;
      sdn[tid] = snew;
      sden[n] = snew;
      mxv[n] = mnew;
    }
  }
  __syncthreads();
  if (last) {
#pragma unroll
    for (int i = 0; i < 16; ++i) {
      int idx = tid + i * 256;
      int row = idx >> 7, col = idx & 127;
      int n = n0 + row;
      if (n < NNODES) {
        float hv = (float)h_lds[row * 132 + col];
        size_t o = (size_t)n * HDIM + col;
        float av = (float)acch[o];
        outf[o] = (av * facs[row] + ps[row] * hv) / sdn[row];
      }
    }
  } else {
#pragma unroll
    for (int i = 0; i < 16; ++i) {
      int idx = tid + i * 256;
      int row = idx >> 7, col = idx & 127;
      int n = n0 + row;
      if (n < NNODES) {
        float hv = (float)h_lds[row * 132 + col];
        size_t o = (size_t)n * HDIM + col;
        float av = (float)acch[o];
        acch[o] = (_Float16)(av * facs[row] + ps[row] * hv);
        hout[o] = (_Float16)hv;
      }
    }
  }
}

extern "C" void kernel_launch(void* const* d_in, const int* in_sizes, int n_in,
                              void* d_out, int out_size, void* d_ws, size_t ws_size,
                              hipStream_t stream) {
  const float* static_dense = (const float*)d_in[0];
  const int*   static_sparse = (const int*)d_in[1];
  const float* dyn_dense = (const float*)d_in[2];
  const int*   dyn_sparse = (const int*)d_in[3];
  const int*   edges = (const int*)d_in[4];
  const float* weights = (const float*)d_in[5];
  const float* s_emb = (const float*)d_in[6];
  const float* d_emb = (const float*)d_in[7];
  const float* Ws = (const float*)d_in[8];
  const float* bs = (const float*)d_in[9];
  const float* gW1 = (const float*)d_in[10];
  const float* gb1 = (const float*)d_in[11];
  const float* gW2 = (const float*)d_in[12];
  const float* gb2 = (const float*)d_in[13];
  const float* Wx = (const float*)d_in[14];
  const float* Wh = (const float*)d_in[15];
  const float* bx = (const float*)d_in[16];
  const float* bh_in = (const float*)d_in[17];
  const float* Waw = (const float*)d_in[18];
  const float* baw = (const float*)d_in[19];
  float* out = (float*)d_out;  // final fp32 output [N,128], written by last gru_mfma

  const size_t N = NNODES;
  char* p = (char*)d_ws;
  auto alloc = [&](size_t bytes) { char* r = p; p += (bytes + 255) & ~(size_t)255; return r; };
  float*     sden   = (float*)alloc(N * 4);
  float*     mxv    = (float*)alloc(N * 4);
  _Float16*  acch   = (_Float16*)alloc(N * HDIM * 2);      // fp16 attention accumulator
  // Big block: loop buffers; tmp (51.2MB) aliases it — tmp is fully consumed by fine_sort
  // BEFORE the loop's first write into any of these (stream order).
  char*      big    = alloc(64UL * 1024 * 1024);
  _Float16*  hA     = (_Float16*)big;                      // 12.8MB
  _Float16*  hB     = hA + N * HDIM;                       // 12.8MB
  _Float16*  dynx   = hB + N * HDIM;                       // 6.4MB
  _Float16*  m1h    = dynx + N * G0DIM;                    // 6.4MB
  _Float16*  h1h    = m1h + N * G0DIM;                     // 12.8MB
  _Float16*  Xh     = h1h + N * HDIM;                      // 12.8MB
  int2*      tmp    = (int2*)big;                          // 51.2MB alias
  float*     Wf32   = (float*)alloc((size_t)TSTEPS * HDIM * H3 * 4);
  _Float16*  Wcombt = (_Float16*)alloc((size_t)TSTEPS * 512 * 256 * 2);
  float*     bfb    = (float*)alloc((size_t)TSTEPS * H3 * 4);
  float*     bcomb  = (float*)alloc((size_t)TSTEPS * 512 * 4);
  int*       bhist  = (int*)alloc((size_t)TSTEPS * NSCN * 4);   // 3.2MB
  int*       bscan  = (int*)alloc((size_t)TSTEPS * NSCN * 4);   // 3.2MB
  int*       csum   = (int*)alloc((size_t)TSTEPS * NCHK2 * 4);
  int*       cbase  = (int*)alloc((size_t)TSTEPS * NCHK2 * 4);
  int*       offs   = (int*)alloc((size_t)TSTEPS * (NKEY + 1) * 4);
  unsigned int* csr = (unsigned int*)alloc((size_t)TSTEPS * NEDGES * 4);  // 25.6MB packed

  // ---- atomic-free two-level counting sort (all timesteps) ----
  coarse_hist<<<dim3(NBLK, TSTEPS), 512, 0, stream>>>(edges, bhist);
  scan_c1<<<TSTEPS * NCHK2, 256, 0, stream>>>(bhist, csum);
  scan_c2<<<TSTEPS, 512, 0, stream>>>(csum, cbase);
  scan_c3<<<TSTEPS * NCHK2, 512, 0, stream>>>(bhist, cbase, bscan);
  coarse_scatter<<<dim3(NBLK, TSTEPS), 512, 0, stream>>>(edges, weights, bscan, tmp);
  fine_sort<<<dim3(COARSE, TSTEPS), 512, 0, stream>>>(bscan, tmp, csr, offs);

  // ---- weight/bias preprocessing ----
  fuse_w<<<TSTEPS * HDIM, H3, 0, stream>>>(gW2, Wx, Wf32);
  fuse_b<<<TSTEPS, H3, 0, stream>>>(gb2, Wx, bx, bfb);
  pack_wcomb<<<TSTEPS * 512, 256, 0, stream>>>(Wf32, Wh, Wcombt);
  pack_bcomb<<<TSTEPS, 512, 0, stream>>>(bfb, bh_in, bcomb);

  static_encode_attn_init<<<NNODES, 128, 0, stream>>>(
      static_dense, static_sparse, s_emb, Ws, bs, Waw, baw, acch, sden, mxv);

  const int GRUB = (NNODES + 31) / 32;
  for (int t = 0; t < TSTEPS; ++t) {
    const int* off_t = offs + (size_t)t * (NKEY + 1);
    const unsigned int* csr_t = csr + (size_t)t * NEDGES;
    _Float16* hcur = (t & 1) ? hB : hA;
    const _Float16* hprev = (t == 0) ? nullptr : ((t & 1) ? hA : hB);

    dynx_gather_h<<<(NNODES * 8 + 255) / 256, 256, 0, stream>>>(
        dyn_dense + (size_t)t * N * DDIM, dyn_sparse + (size_t)t * N * 2, d_emb, dynx);

    gather_merged<G0DIM><<<(NNODES + 31) / 32, 256, 0, stream>>>(off_t, csr_t, dynx, m1h);

    rowmm64<<<NNODES / 8, 64, 0, stream>>>(
        m1h, gW1 + (size_t)t * G0DIM * HDIM, gb1 + (size_t)t * HDIM, h1h);

    gather_merged<HDIM><<<(NNODES + 15) / 16, 256, 0, stream>>>(off_t, csr_t, h1h, Xh);

    gru_mfma<<<GRUB, 256, 0, stream>>>(
        Xh, hprev, Wcombt + (size_t)t * 512 * 256, bcomb + t * 512,
        Waw, baw, hcur, acch, out, sden, mxv, t == TSTEPS - 1 ? 1 : 0);
  }
}

// Round 25
// 1084.622 us; speedup vs baseline: 1.0322x; 1.0322x over previous
//
#include <hip/hip_runtime.h>
#include <hip/hip_bf16.h>
#include <string.h>

#define NNODES 50000
#define TSTEPS 8
#define NEDGES 800000
#define VVOCAB 1000
#define DDIM 32
#define HDIM 128
#define G0DIM 64
#define H3 384
#define NSB 4          // src blocks: key = dst*NSB + src/SRCBLK
#define SRCBLK 12500
#define NKEY (NNODES * NSB)      // 200000 keys per timestep
#define NBLK 256                 // edge blocks per timestep for the sort
#define EPB 3125                 // edges per block (256*3125 = 800000 exactly)
#define COARSE 391               // coarse bins = key>>9 (max key 199999 -> 390)
#define FINEN 512                // fine keys per coarse bin (key & 511)
#define NSCN (COARSE * NBLK)     // 100096
#define NCHK2 196                // ceil(NSCN/512)
#define STAGE_CAP 4096           // LDS staging capacity for fine_sort bins

typedef _Float16 v8h __attribute__((ext_vector_type(8)));
typedef float v4f __attribute__((ext_vector_type(4)));

__device__ __forceinline__ float w_decode(unsigned int packed) {
  unsigned short wb = (unsigned short)(packed >> 16);
  _Float16 h;
  __builtin_memcpy(&h, &wb, 2);
  return (float)h;
}

// ---- fast transcendentals (v_exp_f32 + v_rcp_f32), safe for fp16-precision outputs ------
__device__ __forceinline__ float fsigmoid(float v) {
  return __builtin_amdgcn_rcpf(1.f + __expf(-v));
}
__device__ __forceinline__ float ftanh(float x) {
  float xc = fminf(fmaxf(x, -15.f), 15.f);
  float e2 = __expf(2.f * xc);
  return (e2 - 1.f) * __builtin_amdgcn_rcpf(e2 + 1.f);
}

// ============== Atomic-free two-level counting sort (CSR build) ===========================

// A1: per-block LDS histogram over coarse bins -> bh[t][coarse*NBLK + block]
__global__ __launch_bounds__(512) void coarse_hist(const int* __restrict__ edges,
                                                   int* __restrict__ bh) {
  __shared__ int hist[COARSE];
  int t = blockIdx.y, b = blockIdx.x, tid = threadIdx.x;
  for (int i = tid; i < COARSE; i += 512) hist[i] = 0;
  __syncthreads();
  const int* srcp = edges + (size_t)t * 2 * NEDGES + (size_t)b * EPB;
  const int* dstp = srcp + NEDGES;
  for (int i = tid; i < EPB; i += 512) {
    int key = dstp[i] * NSB + srcp[i] / SRCBLK;
    atomicAdd(&hist[key >> 9], 1);
  }
  __syncthreads();
  for (int i = tid; i < COARSE; i += 512) bh[(size_t)t * NSCN + i * NBLK + b] = hist[i];
}

// scan of bh[t][0..NSCN) -> bscan (exclusive), hierarchical
__global__ __launch_bounds__(256) void scan_c1(const int* __restrict__ bh,
                                               int* __restrict__ csum) {
  int bid = blockIdx.x;  // t*NCHK2 + c
  int t = bid / NCHK2, c = bid % NCHK2;
  int tid = threadIdx.x;
  int s = 0;
#pragma unroll
  for (int i = 0; i < 2; ++i) {
    int n = c * 512 + tid + i * 256;
    if (n < NSCN) s += bh[(size_t)t * NSCN + n];
  }
#pragma unroll
  for (int off = 32; off > 0; off >>= 1) s += __shfl_down(s, off, 64);
  __shared__ int wsum[4];
  if ((tid & 63) == 0) wsum[tid >> 6] = s;
  __syncthreads();
  if (tid == 0) csum[bid] = wsum[0] + wsum[1] + wsum[2] + wsum[3];
}

__global__ __launch_bounds__(512) void scan_c2(const int* __restrict__ csum,
                                               int* __restrict__ cbase) {
  int t = blockIdx.x;
  int tid = threadIdx.x;
  __shared__ int buf[512];
  int own = (tid < NCHK2) ? csum[t * NCHK2 + tid] : 0;
  buf[tid] = own;
  __syncthreads();
  for (int d = 1; d < 512; d <<= 1) {
    int v = (tid >= d) ? buf[tid - d] : 0;
    __syncthreads();
    buf[tid] += v;
    __syncthreads();
  }
  if (tid < NCHK2) cbase[t * NCHK2 + tid] = buf[tid] - own;
}

__global__ __launch_bounds__(512) void scan_c3(const int* __restrict__ bh,
                                               const int* __restrict__ cbase,
                                               int* __restrict__ bscan) {
  int bid = blockIdx.x;
  int t = bid / NCHK2, c = bid % NCHK2;
  int tid = threadIdx.x;
  int n = c * 512 + tid;
  int d = (n < NSCN) ? bh[(size_t)t * NSCN + n] : 0;
  __shared__ int buf[512];
  buf[tid] = d;
  __syncthreads();
  for (int s = 1; s < 512; s <<= 1) {
    int v = (tid >= s) ? buf[tid - s] : 0;
    __syncthreads();
    buf[tid] += v;
    __syncthreads();
  }
  if (n < NSCN) bscan[(size_t)t * NSCN + n] = cbase[bid] + buf[tid] - d;
}

// A3: LDS-staged scatter with recorded bin ids.
__global__ __launch_bounds__(512) void coarse_scatter(
    const int* __restrict__ edges, const float* __restrict__ weights,
    const int* __restrict__ bscan, int2* __restrict__ tmp) {
  __shared__ int hist[COARSE], lstart[COARSE], cur[COARSE], scanb[COARSE];
  __shared__ int2 stage[EPB];                 // 25KB
  __shared__ unsigned short binof[EPB];       // 6.25KB
  int t = blockIdx.y, b = blockIdx.x, tid = threadIdx.x;
  for (int i = tid; i < COARSE; i += 512) hist[i] = 0;
  __syncthreads();
  const int* srcp = edges + (size_t)t * 2 * NEDGES + (size_t)b * EPB;
  const int* dstp = srcp + NEDGES;
  const float* wp = weights + (size_t)t * NEDGES + (size_t)b * EPB;
  for (int i = tid; i < EPB; i += 512) {
    int key = dstp[i] * NSB + srcp[i] / SRCBLK;
    atomicAdd(&hist[key >> 9], 1);
  }
  __syncthreads();
  if (tid < COARSE) scanb[tid] = hist[tid];
  __syncthreads();
  for (int d = 1; d < COARSE; d <<= 1) {
    int v = 0;
    if (tid < COARSE && tid >= d) v = scanb[tid - d];
    __syncthreads();
    if (tid < COARSE) scanb[tid] += v;
    __syncthreads();
  }
  if (tid < COARSE) {
    int ls = scanb[tid] - hist[tid];
    lstart[tid] = ls;
    cur[tid] = ls;
  }
  __syncthreads();
  for (int i = tid; i < EPB; i += 512) {
    int src = srcp[i];
    int key = dstp[i] * NSB + src / SRCBLK;
    int coarse = key >> 9, fine = key & 511;
    int lpos = atomicAdd(&cur[coarse], 1);  // LDS atomic
    int2 pk;
    pk.x = src | (fine << 16);
    pk.y = __float_as_int(wp[i]);
    stage[lpos] = pk;
    binof[lpos] = (unsigned short)coarse;
  }
  __syncthreads();
  for (int j = tid; j < EPB; j += 512) {
    int lo = binof[j];
    int gpos = bscan[(size_t)t * NSCN + lo * NBLK + b] + (j - lstart[lo]);
    tmp[(size_t)t * NEDGES + gpos] = stage[j];
  }
}

// B: per (t,coarse) bin: LDS counting sort over 512 fine keys -> packed 4B csr + offs.
__global__ __launch_bounds__(512) void fine_sort(
    const int* __restrict__ bscan, const int2* __restrict__ tmp,
    unsigned int* __restrict__ csr, int* __restrict__ offs) {
  __shared__ int fhist[FINEN], fbase[FINEN], fcur[FINEN], buf[FINEN];
  __shared__ unsigned int stage[STAGE_CAP];
  int t = blockIdx.y, coarse = blockIdx.x, tid = threadIdx.x;
  int cb0 = bscan[(size_t)t * NSCN + coarse * NBLK];
  int cb1 = (coarse == COARSE - 1) ? NEDGES : bscan[(size_t)t * NSCN + (coarse + 1) * NBLK];
  int size = cb1 - cb0;
  fhist[tid] = 0;
  fcur[tid] = 0;
  __syncthreads();
  const int2* bin = tmp + (size_t)t * NEDGES + cb0;
  for (int i = tid; i < size; i += 512) {
    int fine = (bin[i].x >> 16) & 511;
    atomicAdd(&fhist[fine], 1);
  }
  __syncthreads();
  buf[tid] = fhist[tid];
  __syncthreads();
  for (int d = 1; d < FINEN; d <<= 1) {
    int v = (tid >= d) ? buf[tid - d] : 0;
    __syncthreads();
    buf[tid] += v;
    __syncthreads();
  }
  fbase[tid] = buf[tid] - fhist[tid];
  int key = coarse * FINEN + tid;
  if (key < NKEY) offs[(size_t)t * (NKEY + 1) + key] = cb0 + fbase[tid];
  if (coarse == COARSE - 1 && tid == 0) offs[(size_t)t * (NKEY + 1) + NKEY] = NEDGES;
  __syncthreads();
  unsigned int* outp = csr + (size_t)t * NEDGES + cb0;
  if (size <= STAGE_CAP) {
    for (int i = tid; i < size; i += 512) {
      int2 p = bin[i];
      int fine = (p.x >> 16) & 511;
      int lr = atomicAdd(&fcur[fine], 1);  // LDS atomic
      _Float16 wh = (_Float16)__int_as_float(p.y);
      unsigned short wb;
      __builtin_memcpy(&wb, &wh, 2);
      stage[fbase[fine] + lr] = (unsigned int)(p.x & 0xFFFF) | ((unsigned int)wb << 16);
    }
    __syncthreads();
    for (int i = tid; i < size; i += 512) outp[i] = stage[i];
  } else {
    for (int i = tid; i < size; i += 512) {
      int2 p = bin[i];
      int fine = (p.x >> 16) & 511;
      int lr = atomicAdd(&fcur[fine], 1);  // LDS atomic
      _Float16 wh = (_Float16)__int_as_float(p.y);
      unsigned short wb;
      __builtin_memcpy(&wb, &wh, 2);
      outp[fbase[fine] + lr] = (unsigned int)(p.x & 0xFFFF) | ((unsigned int)wb << 16);
    }
  }
}

// ============== Gathers (4B packed csr entries) ===========================================

template <int D>
__global__ __launch_bounds__(256) void gather_merged(
    const int* __restrict__ off, const unsigned int* __restrict__ csr,
    const _Float16* __restrict__ x, _Float16* __restrict__ m) {
  const int LPN = D / 8;
  int n = blockIdx.x * (256 / LPN) + threadIdx.x / LPN;
  int l = threadIdx.x % LPN;
  if (n >= NNODES) return;
  int s0 = off[n * NSB], s1 = off[(n + 1) * NSB];
  float a0[8], a1[8];
#pragma unroll
  for (int i = 0; i < 8; ++i) { a0[i] = 0.f; a1[i] = 0.f; }
  int e = s0;
  for (; e + 1 < s1; e += 2) {
    unsigned int eA = csr[e], eB = csr[e + 1];
    v8h xA = *(const v8h*)&x[(size_t)(eA & 0xFFFF) * D + l * 8];
    v8h xB = *(const v8h*)&x[(size_t)(eB & 0xFFFF) * D + l * 8];
    float wA = w_decode(eA), wB = w_decode(eB);
#pragma unroll
    for (int i = 0; i < 8; ++i) {
      a0[i] += wA * (float)xA[i];
      a1[i] += wB * (float)xB[i];
    }
  }
  if (e < s1) {
    unsigned int eA = csr[e];
    v8h xA = *(const v8h*)&x[(size_t)(eA & 0xFFFF) * D + l * 8];
    float wA = w_decode(eA);
#pragma unroll
    for (int i = 0; i < 8; ++i) a0[i] += wA * (float)xA[i];
  }
  v8h r;
#pragma unroll
  for (int i = 0; i < 8; ++i) r[i] = (_Float16)(a0[i] + a1[i]);
  *(v8h*)&m[(size_t)n * D + l * 8] = r;
}

// ============== Dense kernels =============================================================

__global__ __launch_bounds__(384) void fuse_w(
    const float* __restrict__ gW2, const float* __restrict__ Wx, float* __restrict__ Wf) {
  int t = blockIdx.x >> 7;
  int k = blockIdx.x & 127;
  int j = threadIdx.x;
  __shared__ float row[HDIM];
  if (j < HDIM) row[j] = gW2[((size_t)t * HDIM + k) * HDIM + j];
  __syncthreads();
  float acc = 0.f;
#pragma unroll 8
  for (int c = 0; c < HDIM; ++c) acc += row[c] * Wx[c * H3 + j];
  Wf[((size_t)t * HDIM + k) * H3 + j] = acc;
}

__global__ __launch_bounds__(384) void fuse_b(
    const float* __restrict__ gb2, const float* __restrict__ Wx,
    const float* __restrict__ bx, float* __restrict__ bf) {
  int t = blockIdx.x;
  int j = threadIdx.x;
  __shared__ float row[HDIM];
  if (j < HDIM) row[j] = gb2[t * HDIM + j];
  __syncthreads();
  float acc = bx[j];
#pragma unroll 8
  for (int c = 0; c < HDIM; ++c) acc += row[c] * Wx[c * H3 + j];
  bf[t * H3 + j] = acc;
}

// pack combined fp16 weights in MFMA-lane-coalesced layout:
// Bp[t][ks(8)][cg(32)][lr(4)][lj(16)] of v8h, where col = cg*16+lj, k = ks*32 + lr*8 + i.
__global__ __launch_bounds__(256) void pack_wcomb(
    const float* __restrict__ Wf32, const float* __restrict__ Wh,
    _Float16* __restrict__ Bp) {
  int t = blockIdx.x >> 9;
  int col = blockIdx.x & 511;
  int k = threadIdx.x;  // 0..255
  float v;
  if (col < 384) {
    if (k < 128) v = Wf32[((size_t)t * HDIM + k) * H3 + col];
    else v = (col < 256) ? Wh[(size_t)(k - 128) * H3 + col] : 0.f;
  } else {
    v = (k < 128) ? 0.f : Wh[(size_t)(k - 128) * H3 + (col - 128)];
  }
  int cg = col >> 4, lj = col & 15;
  int ks = k >> 5, rem = k & 31, lr = rem >> 3, ki = rem & 7;
  size_t idx = ((((((size_t)t * 8 + ks) * 32 + cg) * 4 + lr) * 16 + lj) * 8) + ki;
  Bp[idx] = (_Float16)v;
}

__global__ __launch_bounds__(512) void pack_bcomb(
    const float* __restrict__ bfb, const float* __restrict__ bh,
    float* __restrict__ bcomb) {
  int t = blockIdx.x;
  int c = threadIdx.x;
  float v;
  if (c < 256) v = bfb[t * H3 + c] + bh[c];
  else if (c < 384) v = bfb[t * H3 + c];
  else v = bh[c - 128];
  bcomb[t * 512 + c] = v;
}

// static encoder + attn init, rowmm64-style: 64 thr, NB=8 nodes, 2 cols/thread.
// acch (fp16) = relu(x@Ws+bs); sden = 1; mxv = tanh(se)@Waw + baw.
__global__ __launch_bounds__(64) void static_encode8(
    const float* __restrict__ dense, const int* __restrict__ sparse,
    const float* __restrict__ emb,
    const float* __restrict__ Ws, const float* __restrict__ bs,
    const float* __restrict__ Waw, const float* __restrict__ baw,
    _Float16* __restrict__ acch, float* __restrict__ s, float* __restrict__ mx) {
  const int NB = 8;
  int n0 = blockIdx.x * NB;
  int j = threadIdx.x;  // 0..63
  __shared__ float xT[G0DIM][NB + 1];  // pad 9 -> conflict-spread writes
#pragma unroll
  for (int q = 0; q < NB; ++q) {
    int n = n0 + q;
    float v = 0.f;
    if (n < NNODES) {
      if (j < 16) v = emb[sparse[n * 2 + 0] * 16 + j];
      else if (j < 32) v = emb[VVOCAB * 16 + sparse[n * 2 + 1] * 16 + (j - 16)];
      else v = dense[(size_t)n * DDIM + (j - 32)];
    }
    xT[j][q] = v;
  }
  __syncthreads();
  float acc0[NB], acc1[NB];
#pragma unroll
  for (int q = 0; q < NB; ++q) { acc0[q] = 0.f; acc1[q] = 0.f; }
#pragma unroll 4
  for (int k = 0; k < G0DIM; ++k) {
    float w0 = Ws[(size_t)k * HDIM + j];
    float w1 = Ws[(size_t)k * HDIM + j + 64];
#pragma unroll
    for (int q = 0; q < NB; ++q) {
      float xv = xT[k][q];
      acc0[q] += xv * w0;
      acc1[q] += xv * w1;
    }
  }
  float b0 = bs[j], b1 = bs[j + 64];
  float waw0 = Waw[j], waw1 = Waw[j + 64];
#pragma unroll
  for (int q = 0; q < NB; ++q) {
    int n = n0 + q;
    float a0 = fmaxf(acc0[q] + b0, 0.f);
    float a1 = fmaxf(acc1[q] + b1, 0.f);
    if (n < NNODES) {
      acch[(size_t)n * HDIM + j] = (_Float16)a0;
      acch[(size_t)n * HDIM + j + 64] = (_Float16)a1;
    }
    float v = ftanh(a0) * waw0 + ftanh(a1) * waw1;
#pragma unroll
    for (int off = 32; off > 0; off >>= 1) v += __shfl_down(v, off, 64);
    if (j == 0 && n < NNODES) {
      s[n] = 1.f;
      mx[n] = v + baw[0];
    }
  }
}

__global__ __launch_bounds__(256) void dynx_gather_h(
    const float* __restrict__ dense_t, const int* __restrict__ sparse_t,
    const float* __restrict__ emb, _Float16* __restrict__ xout) {
  int idx = blockIdx.x * 256 + threadIdx.x;  // over N*8
  int n = idx >> 3, k8 = idx & 7;
  if (n >= NNODES) return;
  const float* src;
  if (k8 < 2)
    src = &emb[sparse_t[n * 2 + 0] * 16 + k8 * 8];
  else if (k8 < 4)
    src = &emb[VVOCAB * 16 + sparse_t[n * 2 + 1] * 16 + (k8 - 2) * 8];
  else
    src = &dense_t[n * DDIM + (k8 - 4) * 8];
  float4 f0 = *(const float4*)src;
  float4 f1 = *(const float4*)(src + 4);
  v8h v = {(_Float16)f0.x, (_Float16)f0.y, (_Float16)f0.z, (_Float16)f0.w,
           (_Float16)f1.x, (_Float16)f1.y, (_Float16)f1.z, (_Float16)f1.w};
  *(v8h*)&xout[(size_t)n * G0DIM + k8 * 8] = v;
}

__global__ __launch_bounds__(64) void rowmm64(
    const _Float16* __restrict__ x, const float* __restrict__ W,
    const float* __restrict__ b, _Float16* __restrict__ y) {
  const int NB = 8;
  int n0 = blockIdx.x * NB;
  int j = threadIdx.x;
  __shared__ float xT[G0DIM][12];
#pragma unroll
  for (int q = 0; q < NB; ++q) xT[j][q] = (float)x[(size_t)(n0 + q) * G0DIM + j];
  __syncthreads();
  float acc0[NB], acc1[NB];
#pragma unroll
  for (int q = 0; q < NB; ++q) { acc0[q] = 0.f; acc1[q] = 0.f; }
#pragma unroll 4
  for (int k = 0; k < G0DIM; ++k) {
    float4 a = *(const float4*)&xT[k][0];
    float4 c = *(const float4*)&xT[k][4];
    float w0 = W[(size_t)k * HDIM + j];
    float w1 = W[(size_t)k * HDIM + j + 64];
    acc0[0] += a.x * w0; acc0[1] += a.y * w0; acc0[2] += a.z * w0; acc0[3] += a.w * w0;
    acc0[4] += c.x * w0; acc0[5] += c.y * w0; acc0[6] += c.z * w0; acc0[7] += c.w * w0;
    acc1[0] += a.x * w1; acc1[1] += a.y * w1; acc1[2] += a.z * w1; acc1[3] += a.w * w1;
    acc1[4] += c.x * w1; acc1[5] += c.y * w1; acc1[6] += c.z * w1; acc1[7] += c.w * w1;
  }
  float b0 = b[j], b1 = b[j + 64];
#pragma unroll
  for (int q = 0; q < NB; ++q) {
    y[(size_t)(n0 + q) * HDIM + j] = (_Float16)fmaxf(acc0[q] + b0, 0.f);
    y[(size_t)(n0 + q) * HDIM + j + 64] = (_Float16)fmaxf(acc1[q] + b1, 0.f);
  }
}

// MFMA GRU + attention. Coalesced B layout; fp16 h_lds; fast transcendentals.
__global__ __launch_bounds__(256) void gru_mfma(
    const _Float16* __restrict__ Xh, const _Float16* __restrict__ Hp,
    const _Float16* __restrict__ Bt, const float* __restrict__ bcomb,
    const float* __restrict__ Waw, const float* __restrict__ baw,
    _Float16* __restrict__ hout, _Float16* __restrict__ acch,
    float* __restrict__ outf, float* __restrict__ sden, float* __restrict__ mxv,
    int last) {
  const int AST = 264;
  __shared__ _Float16 A_lds[32 * AST];
  __shared__ _Float16 h_lds[32 * 132];
  __shared__ float lg[32], facs[32], ps[32], sdn[32];
  int tid = threadIdx.x;
  int w = tid >> 6, lane = tid & 63;
  int n0 = blockIdx.x * 32;

#pragma unroll
  for (int i = 0; i < 4; ++i) {
    int cid = tid + i * 256;
    int row = cid >> 5, ch = cid & 31;
    int n = n0 + row;
    v8h v = {(_Float16)0, (_Float16)0, (_Float16)0, (_Float16)0,
             (_Float16)0, (_Float16)0, (_Float16)0, (_Float16)0};
    if (n < NNODES) {
      if (ch < 16) v = *(const v8h*)&Xh[(size_t)n * HDIM + ch * 8];
      else if (Hp) v = *(const v8h*)&Hp[(size_t)n * HDIM + (ch - 16) * 8];
    }
    *(v8h*)&A_lds[row * AST + ch * 8] = v;
  }
  __syncthreads();

  int lj = lane & 15, lr = lane >> 4;
  const v8h* Bp = (const v8h*)Bt;  // [ks][cg][lr][lj] fragments, lane-coalesced
  v4f accf[2][8];
#pragma unroll
  for (int m = 0; m < 2; ++m)
#pragma unroll
    for (int f = 0; f < 8; ++f) accf[m][f] = (v4f){0.f, 0.f, 0.f, 0.f};

  for (int ks = 0; ks < 8; ++ks) {
    v8h a0 = *(const v8h*)&A_lds[lj * AST + ks * 32 + lr * 8];
    v8h a1 = *(const v8h*)&A_lds[(16 + lj) * AST + ks * 32 + lr * 8];
#pragma unroll
    for (int g = 0; g < 4; ++g)
#pragma unroll
      for (int p = 0; p < 2; ++p) {
        int cg = g * 8 + w * 2 + p;
        v8h b = Bp[((ks * 32 + cg) * 4 + lr) * 16 + lj];
        accf[0][g * 2 + p] =
            __builtin_amdgcn_mfma_f32_16x16x32_f16(a0, b, accf[0][g * 2 + p], 0, 0, 0);
        accf[1][g * 2 + p] =
            __builtin_amdgcn_mfma_f32_16x16x32_f16(a1, b, accf[1][g * 2 + p], 0, 0, 0);
      }
  }

#pragma unroll
  for (int p = 0; p < 2; ++p) {
    int j = (w * 2 + p) * 16 + lj;
    float br = bcomb[j], bz = bcomb[128 + j], bxn = bcomb[256 + j], bhn = bcomb[384 + j];
#pragma unroll
    for (int m = 0; m < 2; ++m)
#pragma unroll
      for (int reg = 0; reg < 4; ++reg) {
        int row = m * 16 + lr * 4 + reg;
        float r = fsigmoid(accf[m][0 + p][reg] + br);
        float z = fsigmoid(accf[m][2 + p][reg] + bz);
        float hp = (float)A_lds[row * AST + 128 + j];
        float nc = ftanh(accf[m][4 + p][reg] + bxn + r * (accf[m][6 + p][reg] + bhn));
        h_lds[row * 132 + j] = (_Float16)((1.f - z) * nc + z * hp);
      }
  }
  __syncthreads();

  float waw0 = Waw[lane], waw1 = Waw[lane + 64];
#pragma unroll
  for (int q = 0; q < 8; ++q) {
    int row = w * 8 + q;
    float v = ftanh((float)h_lds[row * 132 + lane]) * waw0 +
              ftanh((float)h_lds[row * 132 + lane + 64]) * waw1;
#pragma unroll
    for (int off = 32; off > 0; off >>= 1) v += __shfl_down(v, off, 64);
    if (lane == 0) lg[row] = v;
  }
  __syncthreads();
  if (tid < 32) {
    int n = n0 + tid;
    if (n < NNODES) {
      float l = lg[tid] + baw[0];
      float m = mxv[n];
      float mnew = fmaxf(m, l);
      float fac = __expf(m - mnew);
      float pp = __expf(l - mnew);
      facs[tid] = fac;
      ps[tid] = pp;
      float snew = sden[n] * fac + pp;
      sdn[tid] = snew;
      sden[n] = snew;
      mxv[n] = mnew;
    }
  }
  __syncthreads();
  if (last) {
#pragma unroll
    for (int i = 0; i < 16; ++i) {
      int idx = tid + i * 256;
      int row = idx >> 7, col = idx & 127;
      int n = n0 + row;
      if (n < NNODES) {
        float hv = (float)h_lds[row * 132 + col];
        size_t o = (size_t)n * HDIM + col;
        float av = (float)acch[o];
        outf[o] = (av * facs[row] + ps[row] * hv) / sdn[row];
      }
    }
  } else {
#pragma unroll
    for (int i = 0; i < 16; ++i) {
      int idx = tid + i * 256;
      int row = idx >> 7, col = idx & 127;
      int n = n0 + row;
      if (n < NNODES) {
        float hv = (float)h_lds[row * 132 + col];
        size_t o = (size_t)n * HDIM + col;
        float av = (float)acch[o];
        acch[o] = (_Float16)(av * facs[row] + ps[row] * hv);
        hout[o] = (_Float16)hv;
      }
    }
  }
}

extern "C" void kernel_launch(void* const* d_in, const int* in_sizes, int n_in,
                              void* d_out, int out_size, void* d_ws, size_t ws_size,
                              hipStream_t stream) {
  const float* static_dense = (const float*)d_in[0];
  const int*   static_sparse = (const int*)d_in[1];
  const float* dyn_dense = (const float*)d_in[2];
  const int*   dyn_sparse = (const int*)d_in[3];
  const int*   edges = (const int*)d_in[4];
  const float* weights = (const float*)d_in[5];
  const float* s_emb = (const float*)d_in[6];
  const float* d_emb = (const float*)d_in[7];
  const float* Ws = (const float*)d_in[8];
  const float* bs = (const float*)d_in[9];
  const float* gW1 = (const float*)d_in[10];
  const float* gb1 = (const float*)d_in[11];
  const float* gW2 = (const float*)d_in[12];
  const float* gb2 = (const float*)d_in[13];
  const float* Wx = (const float*)d_in[14];
  const float* Wh = (const float*)d_in[15];
  const float* bx = (const float*)d_in[16];
  const float* bh_in = (const float*)d_in[17];
  const float* Waw = (const float*)d_in[18];
  const float* baw = (const float*)d_in[19];
  float* out = (float*)d_out;  // final fp32 output [N,128], written by last gru_mfma

  const size_t N = NNODES;
  char* p = (char*)d_ws;
  auto alloc = [&](size_t bytes) { char* r = p; p += (bytes + 255) & ~(size_t)255; return r; };
  float*     sden   = (float*)alloc(N * 4);
  float*     mxv    = (float*)alloc(N * 4);
  _Float16*  acch   = (_Float16*)alloc(N * HDIM * 2);      // fp16 attention accumulator
  // Big block: loop buffers; tmp (51.2MB) aliases it — tmp is fully consumed by fine_sort
  // BEFORE the loop's first write into any of these (stream order).
  char*      big    = alloc(64UL * 1024 * 1024);
  _Float16*  hA     = (_Float16*)big;                      // 12.8MB
  _Float16*  hB     = hA + N * HDIM;                       // 12.8MB
  _Float16*  dynx   = hB + N * HDIM;                       // 6.4MB
  _Float16*  m1h    = dynx + N * G0DIM;                    // 6.4MB
  _Float16*  h1h    = m1h + N * G0DIM;                     // 12.8MB
  _Float16*  Xh     = h1h + N * HDIM;                      // 12.8MB
  int2*      tmp    = (int2*)big;                          // 51.2MB alias
  float*     Wf32   = (float*)alloc((size_t)TSTEPS * HDIM * H3 * 4);
  _Float16*  Wcombt = (_Float16*)alloc((size_t)TSTEPS * 512 * 256 * 2);
  float*     bfb    = (float*)alloc((size_t)TSTEPS * H3 * 4);
  float*     bcomb  = (float*)alloc((size_t)TSTEPS * 512 * 4);
  int*       bhist  = (int*)alloc((size_t)TSTEPS * NSCN * 4);   // 3.2MB
  int*       bscan  = (int*)alloc((size_t)TSTEPS * NSCN * 4);   // 3.2MB
  int*       csum   = (int*)alloc((size_t)TSTEPS * NCHK2 * 4);
  int*       cbase  = (int*)alloc((size_t)TSTEPS * NCHK2 * 4);
  int*       offs   = (int*)alloc((size_t)TSTEPS * (NKEY + 1) * 4);
  unsigned int* csr = (unsigned int*)alloc((size_t)TSTEPS * NEDGES * 4);  // 25.6MB packed

  // ---- atomic-free two-level counting sort (all timesteps) ----
  coarse_hist<<<dim3(NBLK, TSTEPS), 512, 0, stream>>>(edges, bhist);
  scan_c1<<<TSTEPS * NCHK2, 256, 0, stream>>>(bhist, csum);
  scan_c2<<<TSTEPS, 512, 0, stream>>>(csum, cbase);
  scan_c3<<<TSTEPS * NCHK2, 512, 0, stream>>>(bhist, cbase, bscan);
  coarse_scatter<<<dim3(NBLK, TSTEPS), 512, 0, stream>>>(edges, weights, bscan, tmp);
  fine_sort<<<dim3(COARSE, TSTEPS), 512, 0, stream>>>(bscan, tmp, csr, offs);

  // ---- weight/bias preprocessing ----
  fuse_w<<<TSTEPS * HDIM, H3, 0, stream>>>(gW2, Wx, Wf32);
  fuse_b<<<TSTEPS, H3, 0, stream>>>(gb2, Wx, bx, bfb);
  pack_wcomb<<<TSTEPS * 512, 256, 0, stream>>>(Wf32, Wh, Wcombt);
  pack_bcomb<<<TSTEPS, 512, 0, stream>>>(bfb, bh_in, bcomb);

  static_encode8<<<(NNODES + 7) / 8, 64, 0, stream>>>(
      static_dense, static_sparse, s_emb, Ws, bs, Waw, baw, acch, sden, mxv);

  const int GRUB = (NNODES + 31) / 32;
  for (int t = 0; t < TSTEPS; ++t) {
    const int* off_t = offs + (size_t)t * (NKEY + 1);
    const unsigned int* csr_t = csr + (size_t)t * NEDGES;
    _Float16* hcur = (t & 1) ? hB : hA;
    const _Float16* hprev = (t == 0) ? nullptr : ((t & 1) ? hA : hB);

    dynx_gather_h<<<(NNODES * 8 + 255) / 256, 256, 0, stream>>>(
        dyn_dense + (size_t)t * N * DDIM, dyn_sparse + (size_t)t * N * 2, d_emb, dynx);

    gather_merged<G0DIM><<<(NNODES + 31) / 32, 256, 0, stream>>>(off_t, csr_t, dynx, m1h);

    rowmm64<<<NNODES / 8, 64, 0, stream>>>(
        m1h, gW1 + (size_t)t * G0DIM * HDIM, gb1 + (size_t)t * HDIM, h1h);

    gather_merged<HDIM><<<(NNODES + 15) / 16, 256, 0, stream>>>(off_t, csr_t, h1h, Xh);

    gru_mfma<<<GRUB, 256, 0, stream>>>(
        Xh, hprev, Wcombt + (size_t)t * 512 * 256, bcomb + t * 512,
        Waw, baw, hcur, acch, out, sden, mxv, t == TSTEPS - 1 ? 1 : 0);
  }
}

// Round 26
// 980.174 us; speedup vs baseline: 1.1422x; 1.1066x over previous
//
#include <hip/hip_runtime.h>
#include <hip/hip_bf16.h>
#include <string.h>

#define NNODES 50000
#define TSTEPS 8
#define NEDGES 800000
#define VVOCAB 1000
#define DDIM 32
#define HDIM 128
#define G0DIM 64
#define H3 384
#define NSB 4          // src blocks: key = dst*NSB + src/SRCBLK
#define SRCBLK 12500
#define NKEY (NNODES * NSB)      // 200000 keys per timestep
#define NBLK 256                 // edge blocks per timestep for the sort
#define EPB 3125                 // edges per block (256*3125 = 800000 exactly)
#define COARSE 391               // coarse bins = key>>9 (max key 199999 -> 390)
#define FINEN 512                // fine keys per coarse bin (key & 511)
#define NSCN (COARSE * NBLK)     // 100096
#define NCHK2 196                // ceil(NSCN/512)
#define STAGE_CAP 4096           // LDS staging capacity for fine_sort bins

typedef _Float16 v8h __attribute__((ext_vector_type(8)));
typedef float v4f __attribute__((ext_vector_type(4)));

__device__ __forceinline__ float w_decode(unsigned int packed) {
  unsigned short wb = (unsigned short)(packed >> 16);
  _Float16 h;
  __builtin_memcpy(&h, &wb, 2);
  return (float)h;
}

// ---- fast transcendentals (v_exp_f32 + v_rcp_f32), safe for fp16-precision outputs ------
__device__ __forceinline__ float fsigmoid(float v) {
  return __builtin_amdgcn_rcpf(1.f + __expf(-v));
}
__device__ __forceinline__ float ftanh(float x) {
  float xc = fminf(fmaxf(x, -15.f), 15.f);
  float e2 = __expf(2.f * xc);
  return (e2 - 1.f) * __builtin_amdgcn_rcpf(e2 + 1.f);
}

// ============== Atomic-free two-level counting sort (CSR build) ===========================

// A1: per-block LDS histogram over coarse bins -> bh[t][coarse*NBLK + block]
__global__ __launch_bounds__(512) void coarse_hist(const int* __restrict__ edges,
                                                   int* __restrict__ bh) {
  __shared__ int hist[COARSE];
  int t = blockIdx.y, b = blockIdx.x, tid = threadIdx.x;
  for (int i = tid; i < COARSE; i += 512) hist[i] = 0;
  __syncthreads();
  const int* srcp = edges + (size_t)t * 2 * NEDGES + (size_t)b * EPB;
  const int* dstp = srcp + NEDGES;
  for (int i = tid; i < EPB; i += 512) {
    int key = dstp[i] * NSB + srcp[i] / SRCBLK;
    atomicAdd(&hist[key >> 9], 1);
  }
  __syncthreads();
  for (int i = tid; i < COARSE; i += 512) bh[(size_t)t * NSCN + i * NBLK + b] = hist[i];
}

// scan of bh[t][0..NSCN) -> bscan (exclusive), hierarchical
__global__ __launch_bounds__(256) void scan_c1(const int* __restrict__ bh,
                                               int* __restrict__ csum) {
  int bid = blockIdx.x;  // t*NCHK2 + c
  int t = bid / NCHK2, c = bid % NCHK2;
  int tid = threadIdx.x;
  int s = 0;
#pragma unroll
  for (int i = 0; i < 2; ++i) {
    int n = c * 512 + tid + i * 256;
    if (n < NSCN) s += bh[(size_t)t * NSCN + n];
  }
#pragma unroll
  for (int off = 32; off > 0; off >>= 1) s += __shfl_down(s, off, 64);
  __shared__ int wsum[4];
  if ((tid & 63) == 0) wsum[tid >> 6] = s;
  __syncthreads();
  if (tid == 0) csum[bid] = wsum[0] + wsum[1] + wsum[2] + wsum[3];
}

__global__ __launch_bounds__(512) void scan_c2(const int* __restrict__ csum,
                                               int* __restrict__ cbase) {
  int t = blockIdx.x;
  int tid = threadIdx.x;
  __shared__ int buf[512];
  int own = (tid < NCHK2) ? csum[t * NCHK2 + tid] : 0;
  buf[tid] = own;
  __syncthreads();
  for (int d = 1; d < 512; d <<= 1) {
    int v = (tid >= d) ? buf[tid - d] : 0;
    __syncthreads();
    buf[tid] += v;
    __syncthreads();
  }
  if (tid < NCHK2) cbase[t * NCHK2 + tid] = buf[tid] - own;
}

__global__ __launch_bounds__(512) void scan_c3(const int* __restrict__ bh,
                                               const int* __restrict__ cbase,
                                               int* __restrict__ bscan) {
  int bid = blockIdx.x;
  int t = bid / NCHK2, c = bid % NCHK2;
  int tid = threadIdx.x;
  int n = c * 512 + tid;
  int d = (n < NSCN) ? bh[(size_t)t * NSCN + n] : 0;
  __shared__ int buf[512];
  buf[tid] = d;
  __syncthreads();
  for (int s = 1; s < 512; s <<= 1) {
    int v = (tid >= s) ? buf[tid - s] : 0;
    __syncthreads();
    buf[tid] += v;
    __syncthreads();
  }
  if (n < NSCN) bscan[(size_t)t * NSCN + n] = cbase[bid] + buf[tid] - d;
}

// A3: LDS-staged scatter with recorded bin ids.
__global__ __launch_bounds__(512) void coarse_scatter(
    const int* __restrict__ edges, const float* __restrict__ weights,
    const int* __restrict__ bscan, int2* __restrict__ tmp) {
  __shared__ int hist[COARSE], lstart[COARSE], cur[COARSE], scanb[COARSE];
  __shared__ int2 stage[EPB];                 // 25KB
  __shared__ unsigned short binof[EPB];       // 6.25KB
  int t = blockIdx.y, b = blockIdx.x, tid = threadIdx.x;
  for (int i = tid; i < COARSE; i += 512) hist[i] = 0;
  __syncthreads();
  const int* srcp = edges + (size_t)t * 2 * NEDGES + (size_t)b * EPB;
  const int* dstp = srcp + NEDGES;
  const float* wp = weights + (size_t)t * NEDGES + (size_t)b * EPB;
  for (int i = tid; i < EPB; i += 512) {
    int key = dstp[i] * NSB + srcp[i] / SRCBLK;
    atomicAdd(&hist[key >> 9], 1);
  }
  __syncthreads();
  if (tid < COARSE) scanb[tid] = hist[tid];
  __syncthreads();
  for (int d = 1; d < COARSE; d <<= 1) {
    int v = 0;
    if (tid < COARSE && tid >= d) v = scanb[tid - d];
    __syncthreads();
    if (tid < COARSE) scanb[tid] += v;
    __syncthreads();
  }
  if (tid < COARSE) {
    int ls = scanb[tid] - hist[tid];
    lstart[tid] = ls;
    cur[tid] = ls;
  }
  __syncthreads();
  for (int i = tid; i < EPB; i += 512) {
    int src = srcp[i];
    int key = dstp[i] * NSB + src / SRCBLK;
    int coarse = key >> 9, fine = key & 511;
    int lpos = atomicAdd(&cur[coarse], 1);  // LDS atomic
    int2 pk;
    pk.x = src | (fine << 16);
    pk.y = __float_as_int(wp[i]);
    stage[lpos] = pk;
    binof[lpos] = (unsigned short)coarse;
  }
  __syncthreads();
  for (int j = tid; j < EPB; j += 512) {
    int lo = binof[j];
    int gpos = bscan[(size_t)t * NSCN + lo * NBLK + b] + (j - lstart[lo]);
    tmp[(size_t)t * NEDGES + gpos] = stage[j];
  }
}

// B: per (t,coarse) bin: LDS counting sort over 512 fine keys -> packed 4B csr + offs.
__global__ __launch_bounds__(512) void fine_sort(
    const int* __restrict__ bscan, const int2* __restrict__ tmp,
    unsigned int* __restrict__ csr, int* __restrict__ offs) {
  __shared__ int fhist[FINEN], fbase[FINEN], fcur[FINEN], buf[FINEN];
  __shared__ unsigned int stage[STAGE_CAP];
  int t = blockIdx.y, coarse = blockIdx.x, tid = threadIdx.x;
  int cb0 = bscan[(size_t)t * NSCN + coarse * NBLK];
  int cb1 = (coarse == COARSE - 1) ? NEDGES : bscan[(size_t)t * NSCN + (coarse + 1) * NBLK];
  int size = cb1 - cb0;
  fhist[tid] = 0;
  fcur[tid] = 0;
  __syncthreads();
  const int2* bin = tmp + (size_t)t * NEDGES + cb0;
  for (int i = tid; i < size; i += 512) {
    int fine = (bin[i].x >> 16) & 511;
    atomicAdd(&fhist[fine], 1);
  }
  __syncthreads();
  buf[tid] = fhist[tid];
  __syncthreads();
  for (int d = 1; d < FINEN; d <<= 1) {
    int v = (tid >= d) ? buf[tid - d] : 0;
    __syncthreads();
    buf[tid] += v;
    __syncthreads();
  }
  fbase[tid] = buf[tid] - fhist[tid];
  int key = coarse * FINEN + tid;
  if (key < NKEY) offs[(size_t)t * (NKEY + 1) + key] = cb0 + fbase[tid];
  if (coarse == COARSE - 1 && tid == 0) offs[(size_t)t * (NKEY + 1) + NKEY] = NEDGES;
  __syncthreads();
  unsigned int* outp = csr + (size_t)t * NEDGES + cb0;
  if (size <= STAGE_CAP) {
    for (int i = tid; i < size; i += 512) {
      int2 p = bin[i];
      int fine = (p.x >> 16) & 511;
      int lr = atomicAdd(&fcur[fine], 1);  // LDS atomic
      _Float16 wh = (_Float16)__int_as_float(p.y);
      unsigned short wb;
      __builtin_memcpy(&wb, &wh, 2);
      stage[fbase[fine] + lr] = (unsigned int)(p.x & 0xFFFF) | ((unsigned int)wb << 16);
    }
    __syncthreads();
    for (int i = tid; i < size; i += 512) outp[i] = stage[i];
  } else {
    for (int i = tid; i < size; i += 512) {
      int2 p = bin[i];
      int fine = (p.x >> 16) & 511;
      int lr = atomicAdd(&fcur[fine], 1);  // LDS atomic
      _Float16 wh = (_Float16)__int_as_float(p.y);
      unsigned short wb;
      __builtin_memcpy(&wb, &wh, 2);
      outp[fbase[fine] + lr] = (unsigned int)(p.x & 0xFFFF) | ((unsigned int)wb << 16);
    }
  }
}

// ============== Gathers (4B packed csr entries) ===========================================

template <int D>
__global__ __launch_bounds__(256) void gather_merged(
    const int* __restrict__ off, const unsigned int* __restrict__ csr,
    const _Float16* __restrict__ x, _Float16* __restrict__ m) {
  const int LPN = D / 8;
  int n = blockIdx.x * (256 / LPN) + threadIdx.x / LPN;
  int l = threadIdx.x % LPN;
  if (n >= NNODES) return;
  int s0 = off[n * NSB], s1 = off[(n + 1) * NSB];
  float a0[8], a1[8];
#pragma unroll
  for (int i = 0; i < 8; ++i) { a0[i] = 0.f; a1[i] = 0.f; }
  int e = s0;
  for (; e + 1 < s1; e += 2) {
    unsigned int eA = csr[e], eB = csr[e + 1];
    v8h xA = *(const v8h*)&x[(size_t)(eA & 0xFFFF) * D + l * 8];
    v8h xB = *(const v8h*)&x[(size_t)(eB & 0xFFFF) * D + l * 8];
    float wA = w_decode(eA), wB = w_decode(eB);
#pragma unroll
    for (int i = 0; i < 8; ++i) {
      a0[i] += wA * (float)xA[i];
      a1[i] += wB * (float)xB[i];
    }
  }
  if (e < s1) {
    unsigned int eA = csr[e];
    v8h xA = *(const v8h*)&x[(size_t)(eA & 0xFFFF) * D + l * 8];
    float wA = w_decode(eA);
#pragma unroll
    for (int i = 0; i < 8; ++i) a0[i] += wA * (float)xA[i];
  }
  v8h r;
#pragma unroll
  for (int i = 0; i < 8; ++i) r[i] = (_Float16)(a0[i] + a1[i]);
  *(v8h*)&m[(size_t)n * D + l * 8] = r;
}

// ============== Dense kernels =============================================================

__global__ __launch_bounds__(384) void fuse_w(
    const float* __restrict__ gW2, const float* __restrict__ Wx, float* __restrict__ Wf) {
  int t = blockIdx.x >> 7;
  int k = blockIdx.x & 127;
  int j = threadIdx.x;
  __shared__ float row[HDIM];
  if (j < HDIM) row[j] = gW2[((size_t)t * HDIM + k) * HDIM + j];
  __syncthreads();
  float acc = 0.f;
#pragma unroll 8
  for (int c = 0; c < HDIM; ++c) acc += row[c] * Wx[c * H3 + j];
  Wf[((size_t)t * HDIM + k) * H3 + j] = acc;
}

__global__ __launch_bounds__(384) void fuse_b(
    const float* __restrict__ gb2, const float* __restrict__ Wx,
    const float* __restrict__ bx, float* __restrict__ bf) {
  int t = blockIdx.x;
  int j = threadIdx.x;
  __shared__ float row[HDIM];
  if (j < HDIM) row[j] = gb2[t * HDIM + j];
  __syncthreads();
  float acc = bx[j];
#pragma unroll 8
  for (int c = 0; c < HDIM; ++c) acc += row[c] * Wx[c * H3 + j];
  bf[t * H3 + j] = acc;
}

// pack combined fp16 weights in MFMA-lane-coalesced layout:
// Bp[t][ks(8)][cg(32)][lr(4)][lj(16)] of v8h, where col = cg*16+lj, k = ks*32 + lr*8 + i.
__global__ __launch_bounds__(256) void pack_wcomb(
    const float* __restrict__ Wf32, const float* __restrict__ Wh,
    _Float16* __restrict__ Bp) {
  int t = blockIdx.x >> 9;
  int col = blockIdx.x & 511;
  int k = threadIdx.x;  // 0..255
  float v;
  if (col < 384) {
    if (k < 128) v = Wf32[((size_t)t * HDIM + k) * H3 + col];
    else v = (col < 256) ? Wh[(size_t)(k - 128) * H3 + col] : 0.f;
  } else {
    v = (k < 128) ? 0.f : Wh[(size_t)(k - 128) * H3 + (col - 128)];
  }
  int cg = col >> 4, lj = col & 15;
  int ks = k >> 5, rem = k & 31, lr = rem >> 3, ki = rem & 7;
  size_t idx = ((((((size_t)t * 8 + ks) * 32 + cg) * 4 + lr) * 16 + lj) * 8) + ki;
  Bp[idx] = (_Float16)v;
}

__global__ __launch_bounds__(512) void pack_bcomb(
    const float* __restrict__ bfb, const float* __restrict__ bh,
    float* __restrict__ bcomb) {
  int t = blockIdx.x;
  int c = threadIdx.x;
  float v;
  if (c < 256) v = bfb[t * H3 + c] + bh[c];
  else if (c < 384) v = bfb[t * H3 + c];
  else v = bh[c - 128];
  bcomb[t * 512 + c] = v;
}

// static encoder + attn init, rowmm64-style: 64 thr, NB=8 nodes, 2 cols/thread.
__global__ __launch_bounds__(64) void static_encode8(
    const float* __restrict__ dense, const int* __restrict__ sparse,
    const float* __restrict__ emb,
    const float* __restrict__ Ws, const float* __restrict__ bs,
    const float* __restrict__ Waw, const float* __restrict__ baw,
    _Float16* __restrict__ acch, float* __restrict__ s, float* __restrict__ mx) {
  const int NB = 8;
  int n0 = blockIdx.x * NB;
  int j = threadIdx.x;  // 0..63
  __shared__ float xT[G0DIM][NB + 1];
#pragma unroll
  for (int q = 0; q < NB; ++q) {
    int n = n0 + q;
    float v = 0.f;
    if (n < NNODES) {
      if (j < 16) v = emb[sparse[n * 2 + 0] * 16 + j];
      else if (j < 32) v = emb[VVOCAB * 16 + sparse[n * 2 + 1] * 16 + (j - 16)];
      else v = dense[(size_t)n * DDIM + (j - 32)];
    }
    xT[j][q] = v;
  }
  __syncthreads();
  float acc0[NB], acc1[NB];
#pragma unroll
  for (int q = 0; q < NB; ++q) { acc0[q] = 0.f; acc1[q] = 0.f; }
#pragma unroll 4
  for (int k = 0; k < G0DIM; ++k) {
    float w0 = Ws[(size_t)k * HDIM + j];
    float w1 = Ws[(size_t)k * HDIM + j + 64];
#pragma unroll
    for (int q = 0; q < NB; ++q) {
      float xv = xT[k][q];
      acc0[q] += xv * w0;
      acc1[q] += xv * w1;
    }
  }
  float b0 = bs[j], b1 = bs[j + 64];
  float waw0 = Waw[j], waw1 = Waw[j + 64];
#pragma unroll
  for (int q = 0; q < NB; ++q) {
    int n = n0 + q;
    float a0 = fmaxf(acc0[q] + b0, 0.f);
    float a1 = fmaxf(acc1[q] + b1, 0.f);
    if (n < NNODES) {
      acch[(size_t)n * HDIM + j] = (_Float16)a0;
      acch[(size_t)n * HDIM + j + 64] = (_Float16)a1;
    }
    float v = ftanh(a0) * waw0 + ftanh(a1) * waw1;
#pragma unroll
    for (int off = 32; off > 0; off >>= 1) v += __shfl_down(v, off, 64);
    if (j == 0 && n < NNODES) {
      s[n] = 1.f;
      mx[n] = v + baw[0];
    }
  }
}

__global__ __launch_bounds__(256) void dynx_gather_h(
    const float* __restrict__ dense_t, const int* __restrict__ sparse_t,
    const float* __restrict__ emb, _Float16* __restrict__ xout) {
  int idx = blockIdx.x * 256 + threadIdx.x;  // over N*8
  int n = idx >> 3, k8 = idx & 7;
  if (n >= NNODES) return;
  const float* src;
  if (k8 < 2)
    src = &emb[sparse_t[n * 2 + 0] * 16 + k8 * 8];
  else if (k8 < 4)
    src = &emb[VVOCAB * 16 + sparse_t[n * 2 + 1] * 16 + (k8 - 2) * 8];
  else
    src = &dense_t[n * DDIM + (k8 - 4) * 8];
  float4 f0 = *(const float4*)src;
  float4 f1 = *(const float4*)(src + 4);
  v8h v = {(_Float16)f0.x, (_Float16)f0.y, (_Float16)f0.z, (_Float16)f0.w,
           (_Float16)f1.x, (_Float16)f1.y, (_Float16)f1.z, (_Float16)f1.w};
  *(v8h*)&xout[(size_t)n * G0DIM + k8 * 8] = v;
}

__global__ __launch_bounds__(64) void rowmm64(
    const _Float16* __restrict__ x, const float* __restrict__ W,
    const float* __restrict__ b, _Float16* __restrict__ y) {
  const int NB = 8;
  int n0 = blockIdx.x * NB;
  int j = threadIdx.x;
  __shared__ float xT[G0DIM][12];
#pragma unroll
  for (int q = 0; q < NB; ++q) xT[j][q] = (float)x[(size_t)(n0 + q) * G0DIM + j];
  __syncthreads();
  float acc0[NB], acc1[NB];
#pragma unroll
  for (int q = 0; q < NB; ++q) { acc0[q] = 0.f; acc1[q] = 0.f; }
#pragma unroll 4
  for (int k = 0; k < G0DIM; ++k) {
    float4 a = *(const float4*)&xT[k][0];
    float4 c = *(const float4*)&xT[k][4];
    float w0 = W[(size_t)k * HDIM + j];
    float w1 = W[(size_t)k * HDIM + j + 64];
    acc0[0] += a.x * w0; acc0[1] += a.y * w0; acc0[2] += a.z * w0; acc0[3] += a.w * w0;
    acc0[4] += c.x * w0; acc0[5] += c.y * w0; acc0[6] += c.z * w0; acc0[7] += c.w * w0;
    acc1[0] += a.x * w1; acc1[1] += a.y * w1; acc1[2] += a.z * w1; acc1[3] += a.w * w1;
    acc1[4] += c.x * w1; acc1[5] += c.y * w1; acc1[6] += c.z * w1; acc1[7] += c.w * w1;
  }
  float b0 = b[j], b1 = b[j + 64];
#pragma unroll
  for (int q = 0; q < NB; ++q) {
    y[(size_t)(n0 + q) * HDIM + j] = (_Float16)fmaxf(acc0[q] + b0, 0.f);
    y[(size_t)(n0 + q) * HDIM + j + 64] = (_Float16)fmaxf(acc1[q] + b1, 0.f);
  }
}

// MFMA GRU + attention. 64 nodes/block, 8 waves; wave w owns output cols [16w,16w+16)
// via cg = g*8 + w (gate g = acc index). B panel read once per 64 nodes (was per 32).
__global__ __launch_bounds__(512) void gru_mfma(
    const _Float16* __restrict__ Xh, const _Float16* __restrict__ Hp,
    const _Float16* __restrict__ Bt, const float* __restrict__ bcomb,
    const float* __restrict__ Waw, const float* __restrict__ baw,
    _Float16* __restrict__ hout, _Float16* __restrict__ acch,
    float* __restrict__ outf, float* __restrict__ sden, float* __restrict__ mxv,
    int last) {
  const int AST = 264;
  __shared__ _Float16 A_lds[64 * AST];   // 33.8KB
  __shared__ _Float16 h_lds[64 * 132];   // 16.9KB
  __shared__ float lg[64], facs[64], ps[64], sdn[64];
  int tid = threadIdx.x;
  int w = tid >> 6, lane = tid & 63;
  int n0 = blockIdx.x * 64;

#pragma unroll
  for (int i = 0; i < 4; ++i) {
    int cid = tid + i * 512;             // 64 rows x 32 chunks = 2048
    int row = cid >> 5, ch = cid & 31;
    int n = n0 + row;
    v8h v = {(_Float16)0, (_Float16)0, (_Float16)0, (_Float16)0,
             (_Float16)0, (_Float16)0, (_Float16)0, (_Float16)0};
    if (n < NNODES) {
      if (ch < 16) v = *(const v8h*)&Xh[(size_t)n * HDIM + ch * 8];
      else if (Hp) v = *(const v8h*)&Hp[(size_t)n * HDIM + (ch - 16) * 8];
    }
    *(v8h*)&A_lds[row * AST + ch * 8] = v;
  }
  __syncthreads();

  int lj = lane & 15, lr = lane >> 4;
  const v8h* Bp = (const v8h*)Bt;  // [ks][cg][lr][lj] fragments, lane-coalesced
  v4f accf[4][4];                  // [m(4 row tiles)][g(4 gates)]
#pragma unroll
  for (int m = 0; m < 4; ++m)
#pragma unroll
    for (int g = 0; g < 4; ++g) accf[m][g] = (v4f){0.f, 0.f, 0.f, 0.f};

  for (int ks = 0; ks < 8; ++ks) {
    v8h a0 = *(const v8h*)&A_lds[(0 + lj) * AST + ks * 32 + lr * 8];
    v8h a1 = *(const v8h*)&A_lds[(16 + lj) * AST + ks * 32 + lr * 8];
    v8h a2 = *(const v8h*)&A_lds[(32 + lj) * AST + ks * 32 + lr * 8];
    v8h a3 = *(const v8h*)&A_lds[(48 + lj) * AST + ks * 32 + lr * 8];
#pragma unroll
    for (int g = 0; g < 4; ++g) {
      int cg = g * 8 + w;
      v8h b = Bp[((ks * 32 + cg) * 4 + lr) * 16 + lj];
      accf[0][g] = __builtin_amdgcn_mfma_f32_16x16x32_f16(a0, b, accf[0][g], 0, 0, 0);
      accf[1][g] = __builtin_amdgcn_mfma_f32_16x16x32_f16(a1, b, accf[1][g], 0, 0, 0);
      accf[2][g] = __builtin_amdgcn_mfma_f32_16x16x32_f16(a2, b, accf[2][g], 0, 0, 0);
      accf[3][g] = __builtin_amdgcn_mfma_f32_16x16x32_f16(a3, b, accf[3][g], 0, 0, 0);
    }
  }

  {
    int j = w * 16 + lj;  // output col 0..127
    float br = bcomb[j], bz = bcomb[128 + j], bxn = bcomb[256 + j], bhn = bcomb[384 + j];
#pragma unroll
    for (int m = 0; m < 4; ++m)
#pragma unroll
      for (int reg = 0; reg < 4; ++reg) {
        int row = m * 16 + lr * 4 + reg;
        float r = fsigmoid(accf[m][0][reg] + br);
        float z = fsigmoid(accf[m][1][reg] + bz);
        float hp = (float)A_lds[row * AST + 128 + j];
        float nc = ftanh(accf[m][2][reg] + bxn + r * (accf[m][3][reg] + bhn));
        h_lds[row * 132 + j] = (_Float16)((1.f - z) * nc + z * hp);
      }
  }
  __syncthreads();

  float waw0 = Waw[lane], waw1 = Waw[lane + 64];
#pragma unroll
  for (int q = 0; q < 8; ++q) {
    int row = w * 8 + q;  // 8 waves x 8 rows = 64
    float v = ftanh((float)h_lds[row * 132 + lane]) * waw0 +
              ftanh((float)h_lds[row * 132 + lane + 64]) * waw1;
#pragma unroll
    for (int off = 32; off > 0; off >>= 1) v += __shfl_down(v, off, 64);
    if (lane == 0) lg[row] = v;
  }
  __syncthreads();
  if (tid < 64) {
    int n = n0 + tid;
    if (n < NNODES) {
      float l = lg[tid] + baw[0];
      float m = mxv[n];
      float mnew = fmaxf(m, l);
      float fac = __expf(m - mnew);
      float pp = __expf(l - mnew);
      facs[tid] = fac;
      ps[tid] = pp;
      float snew = sden[n] * fac + pp;
      sdn[tid] = snew;
      sden[n] = snew;
      mxv[n] = mnew;
    }
  }
  __syncthreads();
  if (last) {
#pragma unroll
    for (int i = 0; i < 16; ++i) {
      int idx = tid + i * 512;  // 64*128 = 8192
      int row = idx >> 7, col = idx & 127;
      int n = n0 + row;
      if (n < NNODES) {
        float hv = (float)h_lds[row * 132 + col];
        size_t o = (size_t)n * HDIM + col;
        float av = (float)acch[o];
        outf[o] = (av * facs[row] + ps[row] * hv) / sdn[row];
      }
    }
  } else {
#pragma unroll
    for (int i = 0; i < 16; ++i) {
      int idx = tid + i * 512;
      int row = idx >> 7, col = idx & 127;
      int n = n0 + row;
      if (n < NNODES) {
        float hv = (float)h_lds[row * 132 + col];
        size_t o = (size_t)n * HDIM + col;
        float av = (float)acch[o];
        acch[o] = (_Float16)(av * facs[row] + ps[row] * hv);
        hout[o] = (_Float16)hv;
      }
    }
  }
}

extern "C" void kernel_launch(void* const* d_in, const int* in_sizes, int n_in,
                              void* d_out, int out_size, void* d_ws, size_t ws_size,
                              hipStream_t stream) {
  const float* static_dense = (const float*)d_in[0];
  const int*   static_sparse = (const int*)d_in[1];
  const float* dyn_dense = (const float*)d_in[2];
  const int*   dyn_sparse = (const int*)d_in[3];
  const int*   edges = (const int*)d_in[4];
  const float* weights = (const float*)d_in[5];
  const float* s_emb = (const float*)d_in[6];
  const float* d_emb = (const float*)d_in[7];
  const float* Ws = (const float*)d_in[8];
  const float* bs = (const float*)d_in[9];
  const float* gW1 = (const float*)d_in[10];
  const float* gb1 = (const float*)d_in[11];
  const float* gW2 = (const float*)d_in[12];
  const float* gb2 = (const float*)d_in[13];
  const float* Wx = (const float*)d_in[14];
  const float* Wh = (const float*)d_in[15];
  const float* bx = (const float*)d_in[16];
  const float* bh_in = (const float*)d_in[17];
  const float* Waw = (const float*)d_in[18];
  const float* baw = (const float*)d_in[19];
  float* out = (float*)d_out;  // final fp32 output [N,128], written by last gru_mfma

  const size_t N = NNODES;
  char* p = (char*)d_ws;
  auto alloc = [&](size_t bytes) { char* r = p; p += (bytes + 255) & ~(size_t)255; return r; };
  float*     sden   = (float*)alloc(N * 4);
  float*     mxv    = (float*)alloc(N * 4);
  _Float16*  acch   = (_Float16*)alloc(N * HDIM * 2);      // fp16 attention accumulator
  // Big block: loop buffers; tmp (51.2MB) aliases it — tmp is fully consumed by fine_sort
  // BEFORE the loop's first write into any of these (stream order).
  char*      big    = alloc(64UL * 1024 * 1024);
  _Float16*  hA     = (_Float16*)big;                      // 12.8MB
  _Float16*  hB     = hA + N * HDIM;                       // 12.8MB
  _Float16*  dynx   = hB + N * HDIM;                       // 6.4MB
  _Float16*  m1h    = dynx + N * G0DIM;                    // 6.4MB
  _Float16*  h1h    = m1h + N * G0DIM;                     // 12.8MB
  _Float16*  Xh     = h1h + N * HDIM;                      // 12.8MB
  int2*      tmp    = (int2*)big;                          // 51.2MB alias
  float*     Wf32   = (float*)alloc((size_t)TSTEPS * HDIM * H3 * 4);
  _Float16*  Wcombt = (_Float16*)alloc((size_t)TSTEPS * 512 * 256 * 2);
  float*     bfb    = (float*)alloc((size_t)TSTEPS * H3 * 4);
  float*     bcomb  = (float*)alloc((size_t)TSTEPS * 512 * 4);
  int*       bhist  = (int*)alloc((size_t)TSTEPS * NSCN * 4);   // 3.2MB
  int*       bscan  = (int*)alloc((size_t)TSTEPS * NSCN * 4);   // 3.2MB
  int*       csum   = (int*)alloc((size_t)TSTEPS * NCHK2 * 4);
  int*       cbase  = (int*)alloc((size_t)TSTEPS * NCHK2 * 4);
  int*       offs   = (int*)alloc((size_t)TSTEPS * (NKEY + 1) * 4);
  unsigned int* csr = (unsigned int*)alloc((size_t)TSTEPS * NEDGES * 4);  // 25.6MB packed

  // ---- atomic-free two-level counting sort (all timesteps) ----
  coarse_hist<<<dim3(NBLK, TSTEPS), 512, 0, stream>>>(edges, bhist);
  scan_c1<<<TSTEPS * NCHK2, 256, 0, stream>>>(bhist, csum);
  scan_c2<<<TSTEPS, 512, 0, stream>>>(csum, cbase);
  scan_c3<<<TSTEPS * NCHK2, 512, 0, stream>>>(bhist, cbase, bscan);
  coarse_scatter<<<dim3(NBLK, TSTEPS), 512, 0, stream>>>(edges, weights, bscan, tmp);
  fine_sort<<<dim3(COARSE, TSTEPS), 512, 0, stream>>>(bscan, tmp, csr, offs);

  // ---- weight/bias preprocessing ----
  fuse_w<<<TSTEPS * HDIM, H3, 0, stream>>>(gW2, Wx, Wf32);
  fuse_b<<<TSTEPS, H3, 0, stream>>>(gb2, Wx, bx, bfb);
  pack_wcomb<<<TSTEPS * 512, 256, 0, stream>>>(Wf32, Wh, Wcombt);
  pack_bcomb<<<TSTEPS, 512, 0, stream>>>(bfb, bh_in, bcomb);

  static_encode8<<<(NNODES + 7) / 8, 64, 0, stream>>>(
      static_dense, static_sparse, s_emb, Ws, bs, Waw, baw, acch, sden, mxv);

  const int GRUB = (NNODES + 63) / 64;
  for (int t = 0; t < TSTEPS; ++t) {
    const int* off_t = offs + (size_t)t * (NKEY + 1);
    const unsigned int* csr_t = csr + (size_t)t * NEDGES;
    _Float16* hcur = (t & 1) ? hB : hA;
    const _Float16* hprev = (t == 0) ? nullptr : ((t & 1) ? hA : hB);

    dynx_gather_h<<<(NNODES * 8 + 255) / 256, 256, 0, stream>>>(
        dyn_dense + (size_t)t * N * DDIM, dyn_sparse + (size_t)t * N * 2, d_emb, dynx);

    gather_merged<G0DIM><<<(NNODES + 31) / 32, 256, 0, stream>>>(off_t, csr_t, dynx, m1h);

    rowmm64<<<NNODES / 8, 64, 0, stream>>>(
        m1h, gW1 + (size_t)t * G0DIM * HDIM, gb1 + (size_t)t * HDIM, h1h);

    gather_merged<HDIM><<<(NNODES + 15) / 16, 256, 0, stream>>>(off_t, csr_t, h1h, Xh);

    gru_mfma<<<GRUB, 512, 0, stream>>>(
        Xh, hprev, Wcombt + (size_t)t * 512 * 256, bcomb + t * 512,
        Waw, baw, hcur, acch, out, sden, mxv, t == TSTEPS - 1 ? 1 : 0);
  }
}

// Round 27
// 954.546 us; speedup vs baseline: 1.1728x; 1.0268x over previous
//
#include <hip/hip_runtime.h>
#include <hip/hip_bf16.h>
#include <string.h>

#define NNODES 50000
#define TSTEPS 8
#define NEDGES 800000
#define VVOCAB 1000
#define DDIM 32
#define HDIM 128
#define G0DIM 64
#define H3 384
#define NSB 4          // src blocks: key = dst*NSB + src/SRCBLK
#define SRCBLK 12500
#define NKEY (NNODES * NSB)      // 200000 keys per timestep
#define NBLK 256                 // edge blocks per timestep for the sort
#define EPB 3125                 // edges per block (256*3125 = 800000 exactly)
#define COARSE 391               // coarse bins = key>>9 (max key 199999 -> 390)
#define FINEN 512                // fine keys per coarse bin (key & 511)
#define NSCN (COARSE * NBLK)     // 100096
#define NCHK2 196                // ceil(NSCN/512)
#define STAGE_CAP 4096           // LDS staging capacity for fine_sort bins

typedef _Float16 v8h __attribute__((ext_vector_type(8)));
typedef float v4f __attribute__((ext_vector_type(4)));

__device__ __forceinline__ float w_decode(unsigned int packed) {
  unsigned short wb = (unsigned short)(packed >> 16);
  _Float16 h;
  __builtin_memcpy(&h, &wb, 2);
  return (float)h;
}

// ---- fast transcendentals (v_exp_f32 + v_rcp_f32), safe for fp16-precision outputs ------
__device__ __forceinline__ float fsigmoid(float v) {
  return __builtin_amdgcn_rcpf(1.f + __expf(-v));
}
__device__ __forceinline__ float ftanh(float x) {
  float xc = fminf(fmaxf(x, -15.f), 15.f);
  float e2 = __expf(2.f * xc);
  return (e2 - 1.f) * __builtin_amdgcn_rcpf(e2 + 1.f);
}

// ============== Atomic-free two-level counting sort (CSR build) ===========================

// A1: per-block LDS histogram over coarse bins -> bh[t][coarse*NBLK + block]
__global__ __launch_bounds__(512) void coarse_hist(const int* __restrict__ edges,
                                                   int* __restrict__ bh) {
  __shared__ int hist[COARSE];
  int t = blockIdx.y, b = blockIdx.x, tid = threadIdx.x;
  for (int i = tid; i < COARSE; i += 512) hist[i] = 0;
  __syncthreads();
  const int* srcp = edges + (size_t)t * 2 * NEDGES + (size_t)b * EPB;
  const int* dstp = srcp + NEDGES;
  for (int i = tid; i < EPB; i += 512) {
    int key = dstp[i] * NSB + srcp[i] / SRCBLK;
    atomicAdd(&hist[key >> 9], 1);
  }
  __syncthreads();
  for (int i = tid; i < COARSE; i += 512) bh[(size_t)t * NSCN + i * NBLK + b] = hist[i];
}

// scan of bh[t][0..NSCN) -> bscan (exclusive), hierarchical
__global__ __launch_bounds__(256) void scan_c1(const int* __restrict__ bh,
                                               int* __restrict__ csum) {
  int bid = blockIdx.x;  // t*NCHK2 + c
  int t = bid / NCHK2, c = bid % NCHK2;
  int tid = threadIdx.x;
  int s = 0;
#pragma unroll
  for (int i = 0; i < 2; ++i) {
    int n = c * 512 + tid + i * 256;
    if (n < NSCN) s += bh[(size_t)t * NSCN + n];
  }
#pragma unroll
  for (int off = 32; off > 0; off >>= 1) s += __shfl_down(s, off, 64);
  __shared__ int wsum[4];
  if ((tid & 63) == 0) wsum[tid >> 6] = s;
  __syncthreads();
  if (tid == 0) csum[bid] = wsum[0] + wsum[1] + wsum[2] + wsum[3];
}

__global__ __launch_bounds__(512) void scan_c2(const int* __restrict__ csum,
                                               int* __restrict__ cbase) {
  int t = blockIdx.x;
  int tid = threadIdx.x;
  __shared__ int buf[512];
  int own = (tid < NCHK2) ? csum[t * NCHK2 + tid] : 0;
  buf[tid] = own;
  __syncthreads();
  for (int d = 1; d < 512; d <<= 1) {
    int v = (tid >= d) ? buf[tid - d] : 0;
    __syncthreads();
    buf[tid] += v;
    __syncthreads();
  }
  if (tid < NCHK2) cbase[t * NCHK2 + tid] = buf[tid] - own;
}

__global__ __launch_bounds__(512) void scan_c3(const int* __restrict__ bh,
                                               const int* __restrict__ cbase,
                                               int* __restrict__ bscan) {
  int bid = blockIdx.x;
  int t = bid / NCHK2, c = bid % NCHK2;
  int tid = threadIdx.x;
  int n = c * 512 + tid;
  int d = (n < NSCN) ? bh[(size_t)t * NSCN + n] : 0;
  __shared__ int buf[512];
  buf[tid] = d;
  __syncthreads();
  for (int s = 1; s < 512; s <<= 1) {
    int v = (tid >= s) ? buf[tid - s] : 0;
    __syncthreads();
    buf[tid] += v;
    __syncthreads();
  }
  if (n < NSCN) bscan[(size_t)t * NSCN + n] = cbase[bid] + buf[tid] - d;
}

// A3: LDS-staged scatter with recorded bin ids.
__global__ __launch_bounds__(512) void coarse_scatter(
    const int* __restrict__ edges, const float* __restrict__ weights,
    const int* __restrict__ bscan, int2* __restrict__ tmp) {
  __shared__ int hist[COARSE], lstart[COARSE], cur[COARSE], scanb[COARSE];
  __shared__ int2 stage[EPB];                 // 25KB
  __shared__ unsigned short binof[EPB];       // 6.25KB
  int t = blockIdx.y, b = blockIdx.x, tid = threadIdx.x;
  for (int i = tid; i < COARSE; i += 512) hist[i] = 0;
  __syncthreads();
  const int* srcp = edges + (size_t)t * 2 * NEDGES + (size_t)b * EPB;
  const int* dstp = srcp + NEDGES;
  const float* wp = weights + (size_t)t * NEDGES + (size_t)b * EPB;
  for (int i = tid; i < EPB; i += 512) {
    int key = dstp[i] * NSB + srcp[i] / SRCBLK;
    atomicAdd(&hist[key >> 9], 1);
  }
  __syncthreads();
  if (tid < COARSE) scanb[tid] = hist[tid];
  __syncthreads();
  for (int d = 1; d < COARSE; d <<= 1) {
    int v = 0;
    if (tid < COARSE && tid >= d) v = scanb[tid - d];
    __syncthreads();
    if (tid < COARSE) scanb[tid] += v;
    __syncthreads();
  }
  if (tid < COARSE) {
    int ls = scanb[tid] - hist[tid];
    lstart[tid] = ls;
    cur[tid] = ls;
  }
  __syncthreads();
  for (int i = tid; i < EPB; i += 512) {
    int src = srcp[i];
    int key = dstp[i] * NSB + src / SRCBLK;
    int coarse = key >> 9, fine = key & 511;
    int lpos = atomicAdd(&cur[coarse], 1);  // LDS atomic
    int2 pk;
    pk.x = src | (fine << 16);
    pk.y = __float_as_int(wp[i]);
    stage[lpos] = pk;
    binof[lpos] = (unsigned short)coarse;
  }
  __syncthreads();
  for (int j = tid; j < EPB; j += 512) {
    int lo = binof[j];
    int gpos = bscan[(size_t)t * NSCN + lo * NBLK + b] + (j - lstart[lo]);
    tmp[(size_t)t * NEDGES + gpos] = stage[j];
  }
}

// B: per (t,coarse) bin: LDS counting sort over 512 fine keys -> packed 4B csr + offs.
__global__ __launch_bounds__(512) void fine_sort(
    const int* __restrict__ bscan, const int2* __restrict__ tmp,
    unsigned int* __restrict__ csr, int* __restrict__ offs) {
  __shared__ int fhist[FINEN], fbase[FINEN], fcur[FINEN], buf[FINEN];
  __shared__ unsigned int stage[STAGE_CAP];
  int t = blockIdx.y, coarse = blockIdx.x, tid = threadIdx.x;
  int cb0 = bscan[(size_t)t * NSCN + coarse * NBLK];
  int cb1 = (coarse == COARSE - 1) ? NEDGES : bscan[(size_t)t * NSCN + (coarse + 1) * NBLK];
  int size = cb1 - cb0;
  fhist[tid] = 0;
  fcur[tid] = 0;
  __syncthreads();
  const int2* bin = tmp + (size_t)t * NEDGES + cb0;
  for (int i = tid; i < size; i += 512) {
    int fine = (bin[i].x >> 16) & 511;
    atomicAdd(&fhist[fine], 1);
  }
  __syncthreads();
  buf[tid] = fhist[tid];
  __syncthreads();
  for (int d = 1; d < FINEN; d <<= 1) {
    int v = (tid >= d) ? buf[tid - d] : 0;
    __syncthreads();
    buf[tid] += v;
    __syncthreads();
  }
  fbase[tid] = buf[tid] - fhist[tid];
  int key = coarse * FINEN + tid;
  if (key < NKEY) offs[(size_t)t * (NKEY + 1) + key] = cb0 + fbase[tid];
  if (coarse == COARSE - 1 && tid == 0) offs[(size_t)t * (NKEY + 1) + NKEY] = NEDGES;
  __syncthreads();
  unsigned int* outp = csr + (size_t)t * NEDGES + cb0;
  if (size <= STAGE_CAP) {
    for (int i = tid; i < size; i += 512) {
      int2 p = bin[i];
      int fine = (p.x >> 16) & 511;
      int lr = atomicAdd(&fcur[fine], 1);  // LDS atomic
      _Float16 wh = (_Float16)__int_as_float(p.y);
      unsigned short wb;
      __builtin_memcpy(&wb, &wh, 2);
      stage[fbase[fine] + lr] = (unsigned int)(p.x & 0xFFFF) | ((unsigned int)wb << 16);
    }
    __syncthreads();
    for (int i = tid; i < size; i += 512) outp[i] = stage[i];
  } else {
    for (int i = tid; i < size; i += 512) {
      int2 p = bin[i];
      int fine = (p.x >> 16) & 511;
      int lr = atomicAdd(&fcur[fine], 1);  // LDS atomic
      _Float16 wh = (_Float16)__int_as_float(p.y);
      unsigned short wb;
      __builtin_memcpy(&wb, &wh, 2);
      outp[fbase[fine] + lr] = (unsigned int)(p.x & 0xFFFF) | ((unsigned int)wb << 16);
    }
  }
}

// ============== Gather D=128 (4-edge ILP) ==================================================

__global__ __launch_bounds__(256) void gather128(
    const int* __restrict__ off, const unsigned int* __restrict__ csr,
    const _Float16* __restrict__ x, _Float16* __restrict__ m) {
  int n = blockIdx.x * 16 + (threadIdx.x >> 4);
  int l = threadIdx.x & 15;
  if (n >= NNODES) return;
  int s0 = off[n * NSB], s1 = off[(n + 1) * NSB];
  float a0[8], a1[8];
#pragma unroll
  for (int i = 0; i < 8; ++i) { a0[i] = 0.f; a1[i] = 0.f; }
  int e = s0;
  for (; e + 3 < s1; e += 4) {
    unsigned int e0 = csr[e], e1 = csr[e + 1], e2 = csr[e + 2], e3 = csr[e + 3];
    v8h x0 = *(const v8h*)&x[(size_t)(e0 & 0xFFFF) * HDIM + l * 8];
    v8h x1 = *(const v8h*)&x[(size_t)(e1 & 0xFFFF) * HDIM + l * 8];
    v8h x2 = *(const v8h*)&x[(size_t)(e2 & 0xFFFF) * HDIM + l * 8];
    v8h x3 = *(const v8h*)&x[(size_t)(e3 & 0xFFFF) * HDIM + l * 8];
    float w0 = w_decode(e0), w1 = w_decode(e1), w2 = w_decode(e2), w3 = w_decode(e3);
#pragma unroll
    for (int i = 0; i < 8; ++i) {
      a0[i] += w0 * (float)x0[i] + w2 * (float)x2[i];
      a1[i] += w1 * (float)x1[i] + w3 * (float)x3[i];
    }
  }
  for (; e < s1; ++e) {
    unsigned int eA = csr[e];
    v8h xA = *(const v8h*)&x[(size_t)(eA & 0xFFFF) * HDIM + l * 8];
    float wA = w_decode(eA);
#pragma unroll
    for (int i = 0; i < 8; ++i) a0[i] += wA * (float)xA[i];
  }
  v8h r;
#pragma unroll
  for (int i = 0; i < 8; ++i) r[i] = (_Float16)(a0[i] + a1[i]);
  *(v8h*)&m[(size_t)n * HDIM + l * 8] = r;
}

// ============== Fused GCN layer 1: gather(D=64) + rowmm -> h1 (fp16) =====================
// 256 threads, 32 nodes/block. Phase 1: 8 lanes/node gather m1 into regs -> LDS (transposed).
// Phase 2: 4 groups x 64 threads compute relu(m1 @ W1 + b1) for 8 nodes each.
__global__ __launch_bounds__(256) void gcn1_fused(
    const int* __restrict__ off, const unsigned int* __restrict__ csr,
    const _Float16* __restrict__ x, const float* __restrict__ W,
    const float* __restrict__ b, _Float16* __restrict__ y) {
  __shared__ float xT[G0DIM][33];  // [k][node], pad 33 -> low-conflict
  int tid = threadIdx.x;
  int n0 = blockIdx.x * 32;
  {
    int q = tid >> 3, l = tid & 7;  // node slot 0..31, lane 0..7
    int n = n0 + q;
    float a0[8];
#pragma unroll
    for (int i = 0; i < 8; ++i) a0[i] = 0.f;
    if (n < NNODES) {
      int s0 = off[n * NSB], s1 = off[(n + 1) * NSB];
      int e = s0;
      for (; e + 1 < s1; e += 2) {
        unsigned int eA = csr[e], eB = csr[e + 1];
        v8h xA = *(const v8h*)&x[(size_t)(eA & 0xFFFF) * G0DIM + l * 8];
        v8h xB = *(const v8h*)&x[(size_t)(eB & 0xFFFF) * G0DIM + l * 8];
        float wA = w_decode(eA), wB = w_decode(eB);
#pragma unroll
        for (int i = 0; i < 8; ++i) a0[i] += wA * (float)xA[i] + wB * (float)xB[i];
      }
      if (e < s1) {
        unsigned int eA = csr[e];
        v8h xA = *(const v8h*)&x[(size_t)(eA & 0xFFFF) * G0DIM + l * 8];
        float wA = w_decode(eA);
#pragma unroll
        for (int i = 0; i < 8; ++i) a0[i] += wA * (float)xA[i];
      }
    }
#pragma unroll
    for (int i = 0; i < 8; ++i) xT[l * 8 + i][q] = a0[i];
  }
  __syncthreads();
  // rowmm phase: group g2 handles nodes qb..qb+7
  int g2 = tid >> 6, j = tid & 63;
  int qb = g2 * 8;
  float acc0[8], acc1[8];
#pragma unroll
  for (int q = 0; q < 8; ++q) { acc0[q] = 0.f; acc1[q] = 0.f; }
#pragma unroll 4
  for (int k = 0; k < G0DIM; ++k) {
    float w0 = W[(size_t)k * HDIM + j];
    float w1 = W[(size_t)k * HDIM + j + 64];
#pragma unroll
    for (int q = 0; q < 8; ++q) {
      float xv = xT[k][qb + q];
      acc0[q] += xv * w0;
      acc1[q] += xv * w1;
    }
  }
  float b0 = b[j], b1 = b[j + 64];
#pragma unroll
  for (int q = 0; q < 8; ++q) {
    int n = n0 + qb + q;
    if (n < NNODES) {
      y[(size_t)n * HDIM + j] = (_Float16)fmaxf(acc0[q] + b0, 0.f);
      y[(size_t)n * HDIM + j + 64] = (_Float16)fmaxf(acc1[q] + b1, 0.f);
    }
  }
}

// ============== Dense kernels =============================================================

__global__ __launch_bounds__(384) void fuse_w(
    const float* __restrict__ gW2, const float* __restrict__ Wx, float* __restrict__ Wf) {
  int t = blockIdx.x >> 7;
  int k = blockIdx.x & 127;
  int j = threadIdx.x;
  __shared__ float row[HDIM];
  if (j < HDIM) row[j] = gW2[((size_t)t * HDIM + k) * HDIM + j];
  __syncthreads();
  float acc = 0.f;
#pragma unroll 8
  for (int c = 0; c < HDIM; ++c) acc += row[c] * Wx[c * H3 + j];
  Wf[((size_t)t * HDIM + k) * H3 + j] = acc;
}

__global__ __launch_bounds__(384) void fuse_b(
    const float* __restrict__ gb2, const float* __restrict__ Wx,
    const float* __restrict__ bx, float* __restrict__ bf) {
  int t = blockIdx.x;
  int j = threadIdx.x;
  __shared__ float row[HDIM];
  if (j < HDIM) row[j] = gb2[t * HDIM + j];
  __syncthreads();
  float acc = bx[j];
#pragma unroll 8
  for (int c = 0; c < HDIM; ++c) acc += row[c] * Wx[c * H3 + j];
  bf[t * H3 + j] = acc;
}

// pack combined fp16 weights in MFMA-lane-coalesced layout:
// Bp[t][ks(8)][cg(32)][lr(4)][lj(16)] of v8h, where col = cg*16+lj, k = ks*32 + lr*8 + i.
__global__ __launch_bounds__(256) void pack_wcomb(
    const float* __restrict__ Wf32, const float* __restrict__ Wh,
    _Float16* __restrict__ Bp) {
  int t = blockIdx.x >> 9;
  int col = blockIdx.x & 511;
  int k = threadIdx.x;  // 0..255
  float v;
  if (col < 384) {
    if (k < 128) v = Wf32[((size_t)t * HDIM + k) * H3 + col];
    else v = (col < 256) ? Wh[(size_t)(k - 128) * H3 + col] : 0.f;
  } else {
    v = (k < 128) ? 0.f : Wh[(size_t)(k - 128) * H3 + (col - 128)];
  }
  int cg = col >> 4, lj = col & 15;
  int ks = k >> 5, rem = k & 31, lr = rem >> 3, ki = rem & 7;
  size_t idx = ((((((size_t)t * 8 + ks) * 32 + cg) * 4 + lr) * 16 + lj) * 8) + ki;
  Bp[idx] = (_Float16)v;
}

__global__ __launch_bounds__(512) void pack_bcomb(
    const float* __restrict__ bfb, const float* __restrict__ bh,
    float* __restrict__ bcomb) {
  int t = blockIdx.x;
  int c = threadIdx.x;
  float v;
  if (c < 256) v = bfb[t * H3 + c] + bh[c];
  else if (c < 384) v = bfb[t * H3 + c];
  else v = bh[c - 128];
  bcomb[t * 512 + c] = v;
}

// static encoder + attn init, rowmm64-style: 64 thr, NB=8 nodes, 2 cols/thread.
__global__ __launch_bounds__(64) void static_encode8(
    const float* __restrict__ dense, const int* __restrict__ sparse,
    const float* __restrict__ emb,
    const float* __restrict__ Ws, const float* __restrict__ bs,
    const float* __restrict__ Waw, const float* __restrict__ baw,
    _Float16* __restrict__ acch, float* __restrict__ s, float* __restrict__ mx) {
  const int NB = 8;
  int n0 = blockIdx.x * NB;
  int j = threadIdx.x;  // 0..63
  __shared__ float xT[G0DIM][NB + 1];
#pragma unroll
  for (int q = 0; q < NB; ++q) {
    int n = n0 + q;
    float v = 0.f;
    if (n < NNODES) {
      if (j < 16) v = emb[sparse[n * 2 + 0] * 16 + j];
      else if (j < 32) v = emb[VVOCAB * 16 + sparse[n * 2 + 1] * 16 + (j - 16)];
      else v = dense[(size_t)n * DDIM + (j - 32)];
    }
    xT[j][q] = v;
  }
  __syncthreads();
  float acc0[NB], acc1[NB];
#pragma unroll
  for (int q = 0; q < NB; ++q) { acc0[q] = 0.f; acc1[q] = 0.f; }
#pragma unroll 4
  for (int k = 0; k < G0DIM; ++k) {
    float w0 = Ws[(size_t)k * HDIM + j];
    float w1 = Ws[(size_t)k * HDIM + j + 64];
#pragma unroll
    for (int q = 0; q < NB; ++q) {
      float xv = xT[k][q];
      acc0[q] += xv * w0;
      acc1[q] += xv * w1;
    }
  }
  float b0 = bs[j], b1 = bs[j + 64];
  float waw0 = Waw[j], waw1 = Waw[j + 64];
#pragma unroll
  for (int q = 0; q < NB; ++q) {
    int n = n0 + q;
    float a0 = fmaxf(acc0[q] + b0, 0.f);
    float a1 = fmaxf(acc1[q] + b1, 0.f);
    if (n < NNODES) {
      acch[(size_t)n * HDIM + j] = (_Float16)a0;
      acch[(size_t)n * HDIM + j + 64] = (_Float16)a1;
    }
    float v = ftanh(a0) * waw0 + ftanh(a1) * waw1;
#pragma unroll
    for (int off = 32; off > 0; off >>= 1) v += __shfl_down(v, off, 64);
    if (j == 0 && n < NNODES) {
      s[n] = 1.f;
      mx[n] = v + baw[0];
    }
  }
}

__global__ __launch_bounds__(256) void dynx_gather_h(
    const float* __restrict__ dense_t, const int* __restrict__ sparse_t,
    const float* __restrict__ emb, _Float16* __restrict__ xout) {
  int idx = blockIdx.x * 256 + threadIdx.x;  // over N*8
  int n = idx >> 3, k8 = idx & 7;
  if (n >= NNODES) return;
  const float* src;
  if (k8 < 2)
    src = &emb[sparse_t[n * 2 + 0] * 16 + k8 * 8];
  else if (k8 < 4)
    src = &emb[VVOCAB * 16 + sparse_t[n * 2 + 1] * 16 + (k8 - 2) * 8];
  else
    src = &dense_t[n * DDIM + (k8 - 4) * 8];
  float4 f0 = *(const float4*)src;
  float4 f1 = *(const float4*)(src + 4);
  v8h v = {(_Float16)f0.x, (_Float16)f0.y, (_Float16)f0.z, (_Float16)f0.w,
           (_Float16)f1.x, (_Float16)f1.y, (_Float16)f1.z, (_Float16)f1.w};
  *(v8h*)&xout[(size_t)n * G0DIM + k8 * 8] = v;
}

// MFMA GRU + attention. 64 nodes/block, 8 waves; wave w owns output cols [16w,16w+16).
__global__ __launch_bounds__(512) void gru_mfma(
    const _Float16* __restrict__ Xh, const _Float16* __restrict__ Hp,
    const _Float16* __restrict__ Bt, const float* __restrict__ bcomb,
    const float* __restrict__ Waw, const float* __restrict__ baw,
    _Float16* __restrict__ hout, _Float16* __restrict__ acch,
    float* __restrict__ outf, float* __restrict__ sden, float* __restrict__ mxv,
    int last) {
  const int AST = 264;
  __shared__ _Float16 A_lds[64 * AST];   // 33.8KB
  __shared__ _Float16 h_lds[64 * 132];   // 16.9KB
  __shared__ float lg[64], facs[64], ps[64], sdn[64];
  int tid = threadIdx.x;
  int w = tid >> 6, lane = tid & 63;
  int n0 = blockIdx.x * 64;

#pragma unroll
  for (int i = 0; i < 4; ++i) {
    int cid = tid + i * 512;             // 64 rows x 32 chunks = 2048
    int row = cid >> 5, ch = cid & 31;
    int n = n0 + row;
    v8h v = {(_Float16)0, (_Float16)0, (_Float16)0, (_Float16)0,
             (_Float16)0, (_Float16)0, (_Float16)0, (_Float16)0};
    if (n < NNODES) {
      if (ch < 16) v = *(const v8h*)&Xh[(size_t)n * HDIM + ch * 8];
      else if (Hp) v = *(const v8h*)&Hp[(size_t)n * HDIM + (ch - 16) * 8];
    }
    *(v8h*)&A_lds[row * AST + ch * 8] = v;
  }
  __syncthreads();

  int lj = lane & 15, lr = lane >> 4;
  const v8h* Bp = (const v8h*)Bt;  // [ks][cg][lr][lj] fragments, lane-coalesced
  v4f accf[4][4];                  // [m(4 row tiles)][g(4 gates)]
#pragma unroll
  for (int m = 0; m < 4; ++m)
#pragma unroll
    for (int g = 0; g < 4; ++g) accf[m][g] = (v4f){0.f, 0.f, 0.f, 0.f};

  for (int ks = 0; ks < 8; ++ks) {
    v8h a0 = *(const v8h*)&A_lds[(0 + lj) * AST + ks * 32 + lr * 8];
    v8h a1 = *(const v8h*)&A_lds[(16 + lj) * AST + ks * 32 + lr * 8];
    v8h a2 = *(const v8h*)&A_lds[(32 + lj) * AST + ks * 32 + lr * 8];
    v8h a3 = *(const v8h*)&A_lds[(48 + lj) * AST + ks * 32 + lr * 8];
#pragma unroll
    for (int g = 0; g < 4; ++g) {
      int cg = g * 8 + w;
      v8h b = Bp[((ks * 32 + cg) * 4 + lr) * 16 + lj];
      accf[0][g] = __builtin_amdgcn_mfma_f32_16x16x32_f16(a0, b, accf[0][g], 0, 0, 0);
      accf[1][g] = __builtin_amdgcn_mfma_f32_16x16x32_f16(a1, b, accf[1][g], 0, 0, 0);
      accf[2][g] = __builtin_amdgcn_mfma_f32_16x16x32_f16(a2, b, accf[2][g], 0, 0, 0);
      accf[3][g] = __builtin_amdgcn_mfma_f32_16x16x32_f16(a3, b, accf[3][g], 0, 0, 0);
    }
  }

  {
    int j = w * 16 + lj;  // output col 0..127
    float br = bcomb[j], bz = bcomb[128 + j], bxn = bcomb[256 + j], bhn = bcomb[384 + j];
#pragma unroll
    for (int m = 0; m < 4; ++m)
#pragma unroll
      for (int reg = 0; reg < 4; ++reg) {
        int row = m * 16 + lr * 4 + reg;
        float r = fsigmoid(accf[m][0][reg] + br);
        float z = fsigmoid(accf[m][1][reg] + bz);
        float hp = (float)A_lds[row * AST + 128 + j];
        float nc = ftanh(accf[m][2][reg] + bxn + r * (accf[m][3][reg] + bhn));
        h_lds[row * 132 + j] = (_Float16)((1.f - z) * nc + z * hp);
      }
  }
  __syncthreads();

  float waw0 = Waw[lane], waw1 = Waw[lane + 64];
#pragma unroll
  for (int q = 0; q < 8; ++q) {
    int row = w * 8 + q;  // 8 waves x 8 rows = 64
    float v = ftanh((float)h_lds[row * 132 + lane]) * waw0 +
              ftanh((float)h_lds[row * 132 + lane + 64]) * waw1;
#pragma unroll
    for (int off = 32; off > 0; off >>= 1) v += __shfl_down(v, off, 64);
    if (lane == 0) lg[row] = v;
  }
  __syncthreads();
  if (tid < 64) {
    int n = n0 + tid;
    if (n < NNODES) {
      float l = lg[tid] + baw[0];
      float m = mxv[n];
      float mnew = fmaxf(m, l);
      float fac = __expf(m - mnew);
      float pp = __expf(l - mnew);
      facs[tid] = fac;
      ps[tid] = pp;
      float snew = sden[n] * fac + pp;
      sdn[tid] = snew;
      sden[n] = snew;
      mxv[n] = mnew;
    }
  }
  __syncthreads();
  if (last) {
#pragma unroll
    for (int i = 0; i < 16; ++i) {
      int idx = tid + i * 512;  // 64*128 = 8192
      int row = idx >> 7, col = idx & 127;
      int n = n0 + row;
      if (n < NNODES) {
        float hv = (float)h_lds[row * 132 + col];
        size_t o = (size_t)n * HDIM + col;
        float av = (float)acch[o];
        outf[o] = (av * facs[row] + ps[row] * hv) / sdn[row];
      }
    }
  } else {
#pragma unroll
    for (int i = 0; i < 16; ++i) {
      int idx = tid + i * 512;
      int row = idx >> 7, col = idx & 127;
      int n = n0 + row;
      if (n < NNODES) {
        float hv = (float)h_lds[row * 132 + col];
        size_t o = (size_t)n * HDIM + col;
        float av = (float)acch[o];
        acch[o] = (_Float16)(av * facs[row] + ps[row] * hv);
        hout[o] = (_Float16)hv;
      }
    }
  }
}

extern "C" void kernel_launch(void* const* d_in, const int* in_sizes, int n_in,
                              void* d_out, int out_size, void* d_ws, size_t ws_size,
                              hipStream_t stream) {
  const float* static_dense = (const float*)d_in[0];
  const int*   static_sparse = (const int*)d_in[1];
  const float* dyn_dense = (const float*)d_in[2];
  const int*   dyn_sparse = (const int*)d_in[3];
  const int*   edges = (const int*)d_in[4];
  const float* weights = (const float*)d_in[5];
  const float* s_emb = (const float*)d_in[6];
  const float* d_emb = (const float*)d_in[7];
  const float* Ws = (const float*)d_in[8];
  const float* bs = (const float*)d_in[9];
  const float* gW1 = (const float*)d_in[10];
  const float* gb1 = (const float*)d_in[11];
  const float* gW2 = (const float*)d_in[12];
  const float* gb2 = (const float*)d_in[13];
  const float* Wx = (const float*)d_in[14];
  const float* Wh = (const float*)d_in[15];
  const float* bx = (const float*)d_in[16];
  const float* bh_in = (const float*)d_in[17];
  const float* Waw = (const float*)d_in[18];
  const float* baw = (const float*)d_in[19];
  float* out = (float*)d_out;  // final fp32 output [N,128], written by last gru_mfma

  const size_t N = NNODES;
  char* p = (char*)d_ws;
  auto alloc = [&](size_t bytes) { char* r = p; p += (bytes + 255) & ~(size_t)255; return r; };
  float*     sden   = (float*)alloc(N * 4);
  float*     mxv    = (float*)alloc(N * 4);
  _Float16*  acch   = (_Float16*)alloc(N * HDIM * 2);      // fp16 attention accumulator
  // Big block: loop buffers; tmp (51.2MB) aliases it — tmp is fully consumed by fine_sort
  // BEFORE the loop's first write into any of these (stream order).
  char*      big    = alloc(64UL * 1024 * 1024);
  _Float16*  hA     = (_Float16*)big;                      // 12.8MB
  _Float16*  hB     = hA + N * HDIM;                       // 12.8MB
  _Float16*  dynx   = hB + N * HDIM;                       // 6.4MB
  _Float16*  h1h    = dynx + N * G0DIM;                    // 12.8MB
  _Float16*  Xh     = h1h + N * HDIM;                      // 12.8MB
  int2*      tmp    = (int2*)big;                          // 51.2MB alias
  float*     Wf32   = (float*)alloc((size_t)TSTEPS * HDIM * H3 * 4);
  _Float16*  Wcombt = (_Float16*)alloc((size_t)TSTEPS * 512 * 256 * 2);
  float*     bfb    = (float*)alloc((size_t)TSTEPS * H3 * 4);
  float*     bcomb  = (float*)alloc((size_t)TSTEPS * 512 * 4);
  int*       bhist  = (int*)alloc((size_t)TSTEPS * NSCN * 4);   // 3.2MB
  int*       bscan  = (int*)alloc((size_t)TSTEPS * NSCN * 4);   // 3.2MB
  int*       csum   = (int*)alloc((size_t)TSTEPS * NCHK2 * 4);
  int*       cbase  = (int*)alloc((size_t)TSTEPS * NCHK2 * 4);
  int*       offs   = (int*)alloc((size_t)TSTEPS * (NKEY + 1) * 4);
  unsigned int* csr = (unsigned int*)alloc((size_t)TSTEPS * NEDGES * 4);  // 25.6MB packed

  // ---- atomic-free two-level counting sort (all timesteps) ----
  coarse_hist<<<dim3(NBLK, TSTEPS), 512, 0, stream>>>(edges, bhist);
  scan_c1<<<TSTEPS * NCHK2, 256, 0, stream>>>(bhist, csum);
  scan_c2<<<TSTEPS, 512, 0, stream>>>(csum, cbase);
  scan_c3<<<TSTEPS * NCHK2, 512, 0, stream>>>(bhist, cbase, bscan);
  coarse_scatter<<<dim3(NBLK, TSTEPS), 512, 0, stream>>>(edges, weights, bscan, tmp);
  fine_sort<<<dim3(COARSE, TSTEPS), 512, 0, stream>>>(bscan, tmp, csr, offs);

  // ---- weight/bias preprocessing ----
  fuse_w<<<TSTEPS * HDIM, H3, 0, stream>>>(gW2, Wx, Wf32);
  fuse_b<<<TSTEPS, H3, 0, stream>>>(gb2, Wx, bx, bfb);
  pack_wcomb<<<TSTEPS * 512, 256, 0, stream>>>(Wf32, Wh, Wcombt);
  pack_bcomb<<<TSTEPS, 512, 0, stream>>>(bfb, bh_in, bcomb);

  static_encode8<<<(NNODES + 7) / 8, 64, 0, stream>>>(
      static_dense, static_sparse, s_emb, Ws, bs, Waw, baw, acch, sden, mxv);

  const int GRUB = (NNODES + 63) / 64;
  for (int t = 0; t < TSTEPS; ++t) {
    const int* off_t = offs + (size_t)t * (NKEY + 1);
    const unsigned int* csr_t = csr + (size_t)t * NEDGES;
    _Float16* hcur = (t & 1) ? hB : hA;
    const _Float16* hprev = (t == 0) ? nullptr : ((t & 1) ? hA : hB);

    dynx_gather_h<<<(NNODES * 8 + 255) / 256, 256, 0, stream>>>(
        dyn_dense + (size_t)t * N * DDIM, dyn_sparse + (size_t)t * N * 2, d_emb, dynx);

    gcn1_fused<<<(NNODES + 31) / 32, 256, 0, stream>>>(
        off_t, csr_t, dynx, gW1 + (size_t)t * G0DIM * HDIM, gb1 + (size_t)t * HDIM, h1h);

    gather128<<<(NNODES + 15) / 16, 256, 0, stream>>>(off_t, csr_t, h1h, Xh);

    gru_mfma<<<GRUB, 512, 0, stream>>>(
        Xh, hprev, Wcombt + (size_t)t * 512 * 256, bcomb + t * 512,
        Waw, baw, hcur, acch, out, sden, mxv, t == TSTEPS - 1 ? 1 : 0);
  }
}

// Round 28
// 950.474 us; speedup vs baseline: 1.1778x; 1.0043x over previous
//
#include <hip/hip_runtime.h>
#include <hip/hip_bf16.h>
#include <string.h>

#define NNODES 50000
#define TSTEPS 8
#define NEDGES 800000
#define VVOCAB 1000
#define DDIM 32
#define HDIM 128
#define G0DIM 64
#define H3 384
#define NSB 4          // src blocks: key = dst*NSB + src/SRCBLK
#define SRCBLK 12500
#define NKEY (NNODES * NSB)      // 200000 keys per timestep
#define NBLK 256                 // edge blocks per timestep for the sort
#define EPB 3125                 // edges per block (256*3125 = 800000 exactly)
#define COARSE 391               // coarse bins = key>>9 (max key 199999 -> 390)
#define FINEN 512                // fine keys per coarse bin (key & 511)
#define NSCN (COARSE * NBLK)     // 100096
#define NCHK2 196                // ceil(NSCN/512)
#define STAGE_CAP 4096           // LDS staging capacity for fine_sort bins

typedef _Float16 v8h __attribute__((ext_vector_type(8)));
typedef float v4f __attribute__((ext_vector_type(4)));

__device__ __forceinline__ float w_decode(unsigned int packed) {
  unsigned short wb = (unsigned short)(packed >> 16);
  _Float16 h;
  __builtin_memcpy(&h, &wb, 2);
  return (float)h;
}

// ---- fast transcendentals (v_exp_f32 + v_rcp_f32), safe for fp16-precision outputs ------
__device__ __forceinline__ float fsigmoid(float v) {
  return __builtin_amdgcn_rcpf(1.f + __expf(-v));
}
__device__ __forceinline__ float ftanh(float x) {
  float xc = fminf(fmaxf(x, -15.f), 15.f);
  float e2 = __expf(2.f * xc);
  return (e2 - 1.f) * __builtin_amdgcn_rcpf(e2 + 1.f);
}

// ============== Atomic-free two-level counting sort (CSR build) ===========================

// A1: per-block LDS histogram over coarse bins -> bh[t][coarse*NBLK + block]
__global__ __launch_bounds__(512) void coarse_hist(const int* __restrict__ edges,
                                                   int* __restrict__ bh) {
  __shared__ int hist[COARSE];
  int t = blockIdx.y, b = blockIdx.x, tid = threadIdx.x;
  for (int i = tid; i < COARSE; i += 512) hist[i] = 0;
  __syncthreads();
  const int* srcp = edges + (size_t)t * 2 * NEDGES + (size_t)b * EPB;
  const int* dstp = srcp + NEDGES;
  for (int i = tid; i < EPB; i += 512) {
    int key = dstp[i] * NSB + srcp[i] / SRCBLK;
    atomicAdd(&hist[key >> 9], 1);
  }
  __syncthreads();
  for (int i = tid; i < COARSE; i += 512) bh[(size_t)t * NSCN + i * NBLK + b] = hist[i];
}

// scan of bh[t][0..NSCN) -> bscan (exclusive), hierarchical
__global__ __launch_bounds__(256) void scan_c1(const int* __restrict__ bh,
                                               int* __restrict__ csum) {
  int bid = blockIdx.x;  // t*NCHK2 + c
  int t = bid / NCHK2, c = bid % NCHK2;
  int tid = threadIdx.x;
  int s = 0;
#pragma unroll
  for (int i = 0; i < 2; ++i) {
    int n = c * 512 + tid + i * 256;
    if (n < NSCN) s += bh[(size_t)t * NSCN + n];
  }
#pragma unroll
  for (int off = 32; off > 0; off >>= 1) s += __shfl_down(s, off, 64);
  __shared__ int wsum[4];
  if ((tid & 63) == 0) wsum[tid >> 6] = s;
  __syncthreads();
  if (tid == 0) csum[bid] = wsum[0] + wsum[1] + wsum[2] + wsum[3];
}

__global__ __launch_bounds__(512) void scan_c2(const int* __restrict__ csum,
                                               int* __restrict__ cbase) {
  int t = blockIdx.x;
  int tid = threadIdx.x;
  __shared__ int buf[512];
  int own = (tid < NCHK2) ? csum[t * NCHK2 + tid] : 0;
  buf[tid] = own;
  __syncthreads();
  for (int d = 1; d < 512; d <<= 1) {
    int v = (tid >= d) ? buf[tid - d] : 0;
    __syncthreads();
    buf[tid] += v;
    __syncthreads();
  }
  if (tid < NCHK2) cbase[t * NCHK2 + tid] = buf[tid] - own;
}

__global__ __launch_bounds__(512) void scan_c3(const int* __restrict__ bh,
                                               const int* __restrict__ cbase,
                                               int* __restrict__ bscan) {
  int bid = blockIdx.x;
  int t = bid / NCHK2, c = bid % NCHK2;
  int tid = threadIdx.x;
  int n = c * 512 + tid;
  int d = (n < NSCN) ? bh[(size_t)t * NSCN + n] : 0;
  __shared__ int buf[512];
  buf[tid] = d;
  __syncthreads();
  for (int s = 1; s < 512; s <<= 1) {
    int v = (tid >= s) ? buf[tid - s] : 0;
    __syncthreads();
    buf[tid] += v;
    __syncthreads();
  }
  if (n < NSCN) bscan[(size_t)t * NSCN + n] = cbase[bid] + buf[tid] - d;
}

// A3: LDS-staged scatter with recorded bin ids.
__global__ __launch_bounds__(512) void coarse_scatter(
    const int* __restrict__ edges, const float* __restrict__ weights,
    const int* __restrict__ bscan, int2* __restrict__ tmp) {
  __shared__ int hist[COARSE], lstart[COARSE], cur[COARSE], scanb[COARSE];
  __shared__ int2 stage[EPB];                 // 25KB
  __shared__ unsigned short binof[EPB];       // 6.25KB
  int t = blockIdx.y, b = blockIdx.x, tid = threadIdx.x;
  for (int i = tid; i < COARSE; i += 512) hist[i] = 0;
  __syncthreads();
  const int* srcp = edges + (size_t)t * 2 * NEDGES + (size_t)b * EPB;
  const int* dstp = srcp + NEDGES;
  const float* wp = weights + (size_t)t * NEDGES + (size_t)b * EPB;
  for (int i = tid; i < EPB; i += 512) {
    int key = dstp[i] * NSB + srcp[i] / SRCBLK;
    atomicAdd(&hist[key >> 9], 1);
  }
  __syncthreads();
  if (tid < COARSE) scanb[tid] = hist[tid];
  __syncthreads();
  for (int d = 1; d < COARSE; d <<= 1) {
    int v = 0;
    if (tid < COARSE && tid >= d) v = scanb[tid - d];
    __syncthreads();
    if (tid < COARSE) scanb[tid] += v;
    __syncthreads();
  }
  if (tid < COARSE) {
    int ls = scanb[tid] - hist[tid];
    lstart[tid] = ls;
    cur[tid] = ls;
  }
  __syncthreads();
  for (int i = tid; i < EPB; i += 512) {
    int src = srcp[i];
    int key = dstp[i] * NSB + src / SRCBLK;
    int coarse = key >> 9, fine = key & 511;
    int lpos = atomicAdd(&cur[coarse], 1);  // LDS atomic
    int2 pk;
    pk.x = src | (fine << 16);
    pk.y = __float_as_int(wp[i]);
    stage[lpos] = pk;
    binof[lpos] = (unsigned short)coarse;
  }
  __syncthreads();
  for (int j = tid; j < EPB; j += 512) {
    int lo = binof[j];
    int gpos = bscan[(size_t)t * NSCN + lo * NBLK + b] + (j - lstart[lo]);
    tmp[(size_t)t * NEDGES + gpos] = stage[j];
  }
}

// B: per (t,coarse) bin: LDS counting sort over 512 fine keys -> packed 4B csr + offs.
__global__ __launch_bounds__(512) void fine_sort(
    const int* __restrict__ bscan, const int2* __restrict__ tmp,
    unsigned int* __restrict__ csr, int* __restrict__ offs) {
  __shared__ int fhist[FINEN], fbase[FINEN], fcur[FINEN], buf[FINEN];
  __shared__ unsigned int stage[STAGE_CAP];
  int t = blockIdx.y, coarse = blockIdx.x, tid = threadIdx.x;
  int cb0 = bscan[(size_t)t * NSCN + coarse * NBLK];
  int cb1 = (coarse == COARSE - 1) ? NEDGES : bscan[(size_t)t * NSCN + (coarse + 1) * NBLK];
  int size = cb1 - cb0;
  fhist[tid] = 0;
  fcur[tid] = 0;
  __syncthreads();
  const int2* bin = tmp + (size_t)t * NEDGES + cb0;
  for (int i = tid; i < size; i += 512) {
    int fine = (bin[i].x >> 16) & 511;
    atomicAdd(&fhist[fine], 1);
  }
  __syncthreads();
  buf[tid] = fhist[tid];
  __syncthreads();
  for (int d = 1; d < FINEN; d <<= 1) {
    int v = (tid >= d) ? buf[tid - d] : 0;
    __syncthreads();
    buf[tid] += v;
    __syncthreads();
  }
  fbase[tid] = buf[tid] - fhist[tid];
  int key = coarse * FINEN + tid;
  if (key < NKEY) offs[(size_t)t * (NKEY + 1) + key] = cb0 + fbase[tid];
  if (coarse == COARSE - 1 && tid == 0) offs[(size_t)t * (NKEY + 1) + NKEY] = NEDGES;
  __syncthreads();
  unsigned int* outp = csr + (size_t)t * NEDGES + cb0;
  if (size <= STAGE_CAP) {
    for (int i = tid; i < size; i += 512) {
      int2 p = bin[i];
      int fine = (p.x >> 16) & 511;
      int lr = atomicAdd(&fcur[fine], 1);  // LDS atomic
      _Float16 wh = (_Float16)__int_as_float(p.y);
      unsigned short wb;
      __builtin_memcpy(&wb, &wh, 2);
      stage[fbase[fine] + lr] = (unsigned int)(p.x & 0xFFFF) | ((unsigned int)wb << 16);
    }
    __syncthreads();
    for (int i = tid; i < size; i += 512) outp[i] = stage[i];
  } else {
    for (int i = tid; i < size; i += 512) {
      int2 p = bin[i];
      int fine = (p.x >> 16) & 511;
      int lr = atomicAdd(&fcur[fine], 1);  // LDS atomic
      _Float16 wh = (_Float16)__int_as_float(p.y);
      unsigned short wb;
      __builtin_memcpy(&wb, &wh, 2);
      outp[fbase[fine] + lr] = (unsigned int)(p.x & 0xFFFF) | ((unsigned int)wb << 16);
    }
  }
}

// ============== Fused GCN layer 1: gather(D=64) + rowmm -> h1 (fp16) =====================
__global__ __launch_bounds__(256) void gcn1_fused(
    const int* __restrict__ off, const unsigned int* __restrict__ csr,
    const _Float16* __restrict__ x, const float* __restrict__ W,
    const float* __restrict__ b, _Float16* __restrict__ y) {
  __shared__ float xT[G0DIM][33];  // [k][node], pad 33 -> low-conflict
  int tid = threadIdx.x;
  int n0 = blockIdx.x * 32;
  {
    int q = tid >> 3, l = tid & 7;  // node slot 0..31, lane 0..7
    int n = n0 + q;
    float a0[8];
#pragma unroll
    for (int i = 0; i < 8; ++i) a0[i] = 0.f;
    if (n < NNODES) {
      int s0 = off[n * NSB], s1 = off[(n + 1) * NSB];
      int e = s0;
      for (; e + 1 < s1; e += 2) {
        unsigned int eA = csr[e], eB = csr[e + 1];
        v8h xA = *(const v8h*)&x[(size_t)(eA & 0xFFFF) * G0DIM + l * 8];
        v8h xB = *(const v8h*)&x[(size_t)(eB & 0xFFFF) * G0DIM + l * 8];
        float wA = w_decode(eA), wB = w_decode(eB);
#pragma unroll
        for (int i = 0; i < 8; ++i) a0[i] += wA * (float)xA[i] + wB * (float)xB[i];
      }
      if (e < s1) {
        unsigned int eA = csr[e];
        v8h xA = *(const v8h*)&x[(size_t)(eA & 0xFFFF) * G0DIM + l * 8];
        float wA = w_decode(eA);
#pragma unroll
        for (int i = 0; i < 8; ++i) a0[i] += wA * (float)xA[i];
      }
    }
#pragma unroll
    for (int i = 0; i < 8; ++i) xT[l * 8 + i][q] = a0[i];
  }
  __syncthreads();
  int g2 = tid >> 6, j = tid & 63;
  int qb = g2 * 8;
  float acc0[8], acc1[8];
#pragma unroll
  for (int q = 0; q < 8; ++q) { acc0[q] = 0.f; acc1[q] = 0.f; }
#pragma unroll 4
  for (int k = 0; k < G0DIM; ++k) {
    float w0 = W[(size_t)k * HDIM + j];
    float w1 = W[(size_t)k * HDIM + j + 64];
#pragma unroll
    for (int q = 0; q < 8; ++q) {
      float xv = xT[k][qb + q];
      acc0[q] += xv * w0;
      acc1[q] += xv * w1;
    }
  }
  float b0 = b[j], b1 = b[j + 64];
#pragma unroll
  for (int q = 0; q < 8; ++q) {
    int n = n0 + qb + q;
    if (n < NNODES) {
      y[(size_t)n * HDIM + j] = (_Float16)fmaxf(acc0[q] + b0, 0.f);
      y[(size_t)n * HDIM + j + 64] = (_Float16)fmaxf(acc1[q] + b1, 0.f);
    }
  }
}

// ============== Dense kernels =============================================================

__global__ __launch_bounds__(384) void fuse_w(
    const float* __restrict__ gW2, const float* __restrict__ Wx, float* __restrict__ Wf) {
  int t = blockIdx.x >> 7;
  int k = blockIdx.x & 127;
  int j = threadIdx.x;
  __shared__ float row[HDIM];
  if (j < HDIM) row[j] = gW2[((size_t)t * HDIM + k) * HDIM + j];
  __syncthreads();
  float acc = 0.f;
#pragma unroll 8
  for (int c = 0; c < HDIM; ++c) acc += row[c] * Wx[c * H3 + j];
  Wf[((size_t)t * HDIM + k) * H3 + j] = acc;
}

__global__ __launch_bounds__(384) void fuse_b(
    const float* __restrict__ gb2, const float* __restrict__ Wx,
    const float* __restrict__ bx, float* __restrict__ bf) {
  int t = blockIdx.x;
  int j = threadIdx.x;
  __shared__ float row[HDIM];
  if (j < HDIM) row[j] = gb2[t * HDIM + j];
  __syncthreads();
  float acc = bx[j];
#pragma unroll 8
  for (int c = 0; c < HDIM; ++c) acc += row[c] * Wx[c * H3 + j];
  bf[t * H3 + j] = acc;
}

// pack combined fp16 weights in MFMA-lane-coalesced layout:
// Bp[t][ks(8)][cg(32)][lr(4)][lj(16)] of v8h, where col = cg*16+lj, k = ks*32 + lr*8 + i.
__global__ __launch_bounds__(256) void pack_wcomb(
    const float* __restrict__ Wf32, const float* __restrict__ Wh,
    _Float16* __restrict__ Bp) {
  int t = blockIdx.x >> 9;
  int col = blockIdx.x & 511;
  int k = threadIdx.x;  // 0..255
  float v;
  if (col < 384) {
    if (k < 128) v = Wf32[((size_t)t * HDIM + k) * H3 + col];
    else v = (col < 256) ? Wh[(size_t)(k - 128) * H3 + col] : 0.f;
  } else {
    v = (k < 128) ? 0.f : Wh[(size_t)(k - 128) * H3 + (col - 128)];
  }
  int cg = col >> 4, lj = col & 15;
  int ks = k >> 5, rem = k & 31, lr = rem >> 3, ki = rem & 7;
  size_t idx = ((((((size_t)t * 8 + ks) * 32 + cg) * 4 + lr) * 16 + lj) * 8) + ki;
  Bp[idx] = (_Float16)v;
}

__global__ __launch_bounds__(512) void pack_bcomb(
    const float* __restrict__ bfb, const float* __restrict__ bh,
    float* __restrict__ bcomb) {
  int t = blockIdx.x;
  int c = threadIdx.x;
  float v;
  if (c < 256) v = bfb[t * H3 + c] + bh[c];
  else if (c < 384) v = bfb[t * H3 + c];
  else v = bh[c - 128];
  bcomb[t * 512 + c] = v;
}

// static encoder + attn init, rowmm64-style: 64 thr, NB=8 nodes, 2 cols/thread.
__global__ __launch_bounds__(64) void static_encode8(
    const float* __restrict__ dense, const int* __restrict__ sparse,
    const float* __restrict__ emb,
    const float* __restrict__ Ws, const float* __restrict__ bs,
    const float* __restrict__ Waw, const float* __restrict__ baw,
    _Float16* __restrict__ acch, float* __restrict__ s, float* __restrict__ mx) {
  const int NB = 8;
  int n0 = blockIdx.x * NB;
  int j = threadIdx.x;  // 0..63
  __shared__ float xT[G0DIM][NB + 1];
#pragma unroll
  for (int q = 0; q < NB; ++q) {
    int n = n0 + q;
    float v = 0.f;
    if (n < NNODES) {
      if (j < 16) v = emb[sparse[n * 2 + 0] * 16 + j];
      else if (j < 32) v = emb[VVOCAB * 16 + sparse[n * 2 + 1] * 16 + (j - 16)];
      else v = dense[(size_t)n * DDIM + (j - 32)];
    }
    xT[j][q] = v;
  }
  __syncthreads();
  float acc0[NB], acc1[NB];
#pragma unroll
  for (int q = 0; q < NB; ++q) { acc0[q] = 0.f; acc1[q] = 0.f; }
#pragma unroll 4
  for (int k = 0; k < G0DIM; ++k) {
    float w0 = Ws[(size_t)k * HDIM + j];
    float w1 = Ws[(size_t)k * HDIM + j + 64];
#pragma unroll
    for (int q = 0; q < NB; ++q) {
      float xv = xT[k][q];
      acc0[q] += xv * w0;
      acc1[q] += xv * w1;
    }
  }
  float b0 = bs[j], b1 = bs[j + 64];
  float waw0 = Waw[j], waw1 = Waw[j + 64];
#pragma unroll
  for (int q = 0; q < NB; ++q) {
    int n = n0 + q;
    float a0 = fmaxf(acc0[q] + b0, 0.f);
    float a1 = fmaxf(acc1[q] + b1, 0.f);
    if (n < NNODES) {
      acch[(size_t)n * HDIM + j] = (_Float16)a0;
      acch[(size_t)n * HDIM + j + 64] = (_Float16)a1;
    }
    float v = ftanh(a0) * waw0 + ftanh(a1) * waw1;
#pragma unroll
    for (int off = 32; off > 0; off >>= 1) v += __shfl_down(v, off, 64);
    if (j == 0 && n < NNODES) {
      s[n] = 1.f;
      mx[n] = v + baw[0];
    }
  }
}

__global__ __launch_bounds__(256) void dynx_gather_h(
    const float* __restrict__ dense_t, const int* __restrict__ sparse_t,
    const float* __restrict__ emb, _Float16* __restrict__ xout) {
  int idx = blockIdx.x * 256 + threadIdx.x;  // over N*8
  int n = idx >> 3, k8 = idx & 7;
  if (n >= NNODES) return;
  const float* src;
  if (k8 < 2)
    src = &emb[sparse_t[n * 2 + 0] * 16 + k8 * 8];
  else if (k8 < 4)
    src = &emb[VVOCAB * 16 + sparse_t[n * 2 + 1] * 16 + (k8 - 2) * 8];
  else
    src = &dense_t[n * DDIM + (k8 - 4) * 8];
  float4 f0 = *(const float4*)src;
  float4 f1 = *(const float4*)(src + 4);
  v8h v = {(_Float16)f0.x, (_Float16)f0.y, (_Float16)f0.z, (_Float16)f0.w,
           (_Float16)f1.x, (_Float16)f1.y, (_Float16)f1.z, (_Float16)f1.w};
  *(v8h*)&xout[(size_t)n * G0DIM + k8 * 8] = v;
}

// MFMA GRU + attention with FUSED edge-gather prologue: 64 nodes/block, 8 waves.
// Prologue gathers Xh = segment_sum(w * h1[src]) for this block's nodes directly
// from h1h into A_lds (2 passes x 32 nodes x 16 lanes, 4-edge ILP).
__global__ __launch_bounds__(512) void gru_mfma(
    const int* __restrict__ off, const unsigned int* __restrict__ csr,
    const _Float16* __restrict__ x, const _Float16* __restrict__ Hp,
    const _Float16* __restrict__ Bt, const float* __restrict__ bcomb,
    const float* __restrict__ Waw, const float* __restrict__ baw,
    _Float16* __restrict__ hout, _Float16* __restrict__ acch,
    float* __restrict__ outf, float* __restrict__ sden, float* __restrict__ mxv,
    int last) {
  const int AST = 264;
  __shared__ _Float16 A_lds[64 * AST];   // 33.8KB
  __shared__ _Float16 h_lds[64 * 132];   // 16.9KB
  __shared__ float lg[64], facs[64], ps[64], sdn[64];
  int tid = threadIdx.x;
  int w = tid >> 6, lane = tid & 63;
  int n0 = blockIdx.x * 64;

  // stage Hp into cols 128..255 of A_lds
#pragma unroll
  for (int i = 0; i < 2; ++i) {
    int cid = tid + i * 512;             // 64 rows x 16 chunks = 1024
    int row = cid >> 4, ch = cid & 15;
    int n = n0 + row;
    v8h v = {(_Float16)0, (_Float16)0, (_Float16)0, (_Float16)0,
             (_Float16)0, (_Float16)0, (_Float16)0, (_Float16)0};
    if (n < NNODES && Hp) v = *(const v8h*)&Hp[(size_t)n * HDIM + ch * 8];
    *(v8h*)&A_lds[row * AST + 128 + ch * 8] = v;
  }
  // fused gather: Xh part (cols 0..127) directly from h1h via CSR
  {
    int qb = tid >> 4, l = tid & 15;     // 32 node slots, 16 lanes
#pragma unroll
    for (int half = 0; half < 2; ++half) {
      int q = qb + half * 32;
      int n = n0 + q;
      float a0[8], a1[8];
#pragma unroll
      for (int i = 0; i < 8; ++i) { a0[i] = 0.f; a1[i] = 0.f; }
      if (n < NNODES) {
        int s0 = off[n * NSB], s1 = off[(n + 1) * NSB];
        int e = s0;
        for (; e + 3 < s1; e += 4) {
          unsigned int e0 = csr[e], e1 = csr[e + 1], e2 = csr[e + 2], e3 = csr[e + 3];
          v8h x0 = *(const v8h*)&x[(size_t)(e0 & 0xFFFF) * HDIM + l * 8];
          v8h x1 = *(const v8h*)&x[(size_t)(e1 & 0xFFFF) * HDIM + l * 8];
          v8h x2 = *(const v8h*)&x[(size_t)(e2 & 0xFFFF) * HDIM + l * 8];
          v8h x3 = *(const v8h*)&x[(size_t)(e3 & 0xFFFF) * HDIM + l * 8];
          float w0 = w_decode(e0), w1 = w_decode(e1), w2 = w_decode(e2), w3 = w_decode(e3);
#pragma unroll
          for (int i = 0; i < 8; ++i) {
            a0[i] += w0 * (float)x0[i] + w2 * (float)x2[i];
            a1[i] += w1 * (float)x1[i] + w3 * (float)x3[i];
          }
        }
        for (; e < s1; ++e) {
          unsigned int eA = csr[e];
          v8h xA = *(const v8h*)&x[(size_t)(eA & 0xFFFF) * HDIM + l * 8];
          float wA = w_decode(eA);
#pragma unroll
          for (int i = 0; i < 8; ++i) a0[i] += wA * (float)xA[i];
        }
      }
      v8h r;
#pragma unroll
      for (int i = 0; i < 8; ++i) r[i] = (_Float16)(a0[i] + a1[i]);
      *(v8h*)&A_lds[q * AST + l * 8] = r;
    }
  }
  __syncthreads();

  int lj = lane & 15, lr = lane >> 4;
  const v8h* Bp = (const v8h*)Bt;  // [ks][cg][lr][lj] fragments, lane-coalesced
  v4f accf[4][4];                  // [m(4 row tiles)][g(4 gates)]
#pragma unroll
  for (int m = 0; m < 4; ++m)
#pragma unroll
    for (int g = 0; g < 4; ++g) accf[m][g] = (v4f){0.f, 0.f, 0.f, 0.f};

  for (int ks = 0; ks < 8; ++ks) {
    v8h a0 = *(const v8h*)&A_lds[(0 + lj) * AST + ks * 32 + lr * 8];
    v8h a1 = *(const v8h*)&A_lds[(16 + lj) * AST + ks * 32 + lr * 8];
    v8h a2 = *(const v8h*)&A_lds[(32 + lj) * AST + ks * 32 + lr * 8];
    v8h a3 = *(const v8h*)&A_lds[(48 + lj) * AST + ks * 32 + lr * 8];
#pragma unroll
    for (int g = 0; g < 4; ++g) {
      int cg = g * 8 + w;
      v8h b = Bp[((ks * 32 + cg) * 4 + lr) * 16 + lj];
      accf[0][g] = __builtin_amdgcn_mfma_f32_16x16x32_f16(a0, b, accf[0][g], 0, 0, 0);
      accf[1][g] = __builtin_amdgcn_mfma_f32_16x16x32_f16(a1, b, accf[1][g], 0, 0, 0);
      accf[2][g] = __builtin_amdgcn_mfma_f32_16x16x32_f16(a2, b, accf[2][g], 0, 0, 0);
      accf[3][g] = __builtin_amdgcn_mfma_f32_16x16x32_f16(a3, b, accf[3][g], 0, 0, 0);
    }
  }

  {
    int j = w * 16 + lj;  // output col 0..127
    float br = bcomb[j], bz = bcomb[128 + j], bxn = bcomb[256 + j], bhn = bcomb[384 + j];
#pragma unroll
    for (int m = 0; m < 4; ++m)
#pragma unroll
      for (int reg = 0; reg < 4; ++reg) {
        int row = m * 16 + lr * 4 + reg;
        float r = fsigmoid(accf[m][0][reg] + br);
        float z = fsigmoid(accf[m][1][reg] + bz);
        float hp = (float)A_lds[row * AST + 128 + j];
        float nc = ftanh(accf[m][2][reg] + bxn + r * (accf[m][3][reg] + bhn));
        h_lds[row * 132 + j] = (_Float16)((1.f - z) * nc + z * hp);
      }
  }
  __syncthreads();

  float waw0 = Waw[lane], waw1 = Waw[lane + 64];
#pragma unroll
  for (int q = 0; q < 8; ++q) {
    int row = w * 8 + q;  // 8 waves x 8 rows = 64
    float v = ftanh((float)h_lds[row * 132 + lane]) * waw0 +
              ftanh((float)h_lds[row * 132 + lane + 64]) * waw1;
#pragma unroll
    for (int off2 = 32; off2 > 0; off2 >>= 1) v += __shfl_down(v, off2, 64);
    if (lane == 0) lg[row] = v;
  }
  __syncthreads();
  if (tid < 64) {
    int n = n0 + tid;
    if (n < NNODES) {
      float l = lg[tid] + baw[0];
      float m = mxv[n];
      float mnew = fmaxf(m, l);
      float fac = __expf(m - mnew);
      float pp = __expf(l - mnew);
      facs[tid] = fac;
      ps[tid] = pp;
      float snew = sden[n] * fac + pp;
      sdn[tid] = snew;
      sden[n] = snew;
      mxv[n] = mnew;
    }
  }
  __syncthreads();
  if (last) {
#pragma unroll
    for (int i = 0; i < 16; ++i) {
      int idx = tid + i * 512;  // 64*128 = 8192
      int row = idx >> 7, col = idx & 127;
      int n = n0 + row;
      if (n < NNODES) {
        float hv = (float)h_lds[row * 132 + col];
        size_t o = (size_t)n * HDIM + col;
        float av = (float)acch[o];
        outf[o] = (av * facs[row] + ps[row] * hv) / sdn[row];
      }
    }
  } else {
#pragma unroll
    for (int i = 0; i < 16; ++i) {
      int idx = tid + i * 512;
      int row = idx >> 7, col = idx & 127;
      int n = n0 + row;
      if (n < NNODES) {
        float hv = (float)h_lds[row * 132 + col];
        size_t o = (size_t)n * HDIM + col;
        float av = (float)acch[o];
        acch[o] = (_Float16)(av * facs[row] + ps[row] * hv);
        hout[o] = (_Float16)hv;
      }
    }
  }
}

extern "C" void kernel_launch(void* const* d_in, const int* in_sizes, int n_in,
                              void* d_out, int out_size, void* d_ws, size_t ws_size,
                              hipStream_t stream) {
  const float* static_dense = (const float*)d_in[0];
  const int*   static_sparse = (const int*)d_in[1];
  const float* dyn_dense = (const float*)d_in[2];
  const int*   dyn_sparse = (const int*)d_in[3];
  const int*   edges = (const int*)d_in[4];
  const float* weights = (const float*)d_in[5];
  const float* s_emb = (const float*)d_in[6];
  const float* d_emb = (const float*)d_in[7];
  const float* Ws = (const float*)d_in[8];
  const float* bs = (const float*)d_in[9];
  const float* gW1 = (const float*)d_in[10];
  const float* gb1 = (const float*)d_in[11];
  const float* gW2 = (const float*)d_in[12];
  const float* gb2 = (const float*)d_in[13];
  const float* Wx = (const float*)d_in[14];
  const float* Wh = (const float*)d_in[15];
  const float* bx = (const float*)d_in[16];
  const float* bh_in = (const float*)d_in[17];
  const float* Waw = (const float*)d_in[18];
  const float* baw = (const float*)d_in[19];
  float* out = (float*)d_out;  // final fp32 output [N,128], written by last gru_mfma

  const size_t N = NNODES;
  char* p = (char*)d_ws;
  auto alloc = [&](size_t bytes) { char* r = p; p += (bytes + 255) & ~(size_t)255; return r; };
  float*     sden   = (float*)alloc(N * 4);
  float*     mxv    = (float*)alloc(N * 4);
  _Float16*  acch   = (_Float16*)alloc(N * HDIM * 2);      // fp16 attention accumulator
  // Big block: loop buffers; tmp (51.2MB) aliases it — tmp is fully consumed by fine_sort
  // BEFORE the loop's first write into any of these (stream order).
  char*      big    = alloc(64UL * 1024 * 1024);
  _Float16*  hA     = (_Float16*)big;                      // 12.8MB
  _Float16*  hB     = hA + N * HDIM;                       // 12.8MB
  _Float16*  dynx   = hB + N * HDIM;                       // 6.4MB
  _Float16*  h1h    = dynx + N * G0DIM;                    // 12.8MB
  int2*      tmp    = (int2*)big;                          // 51.2MB alias
  float*     Wf32   = (float*)alloc((size_t)TSTEPS * HDIM * H3 * 4);
  _Float16*  Wcombt = (_Float16*)alloc((size_t)TSTEPS * 512 * 256 * 2);
  float*     bfb    = (float*)alloc((size_t)TSTEPS * H3 * 4);
  float*     bcomb  = (float*)alloc((size_t)TSTEPS * 512 * 4);
  int*       bhist  = (int*)alloc((size_t)TSTEPS * NSCN * 4);   // 3.2MB
  int*       bscan  = (int*)alloc((size_t)TSTEPS * NSCN * 4);   // 3.2MB
  int*       csum   = (int*)alloc((size_t)TSTEPS * NCHK2 * 4);
  int*       cbase  = (int*)alloc((size_t)TSTEPS * NCHK2 * 4);
  int*       offs   = (int*)alloc((size_t)TSTEPS * (NKEY + 1) * 4);
  unsigned int* csr = (unsigned int*)alloc((size_t)TSTEPS * NEDGES * 4);  // 25.6MB packed

  // ---- atomic-free two-level counting sort (all timesteps) ----
  coarse_hist<<<dim3(NBLK, TSTEPS), 512, 0, stream>>>(edges, bhist);
  scan_c1<<<TSTEPS * NCHK2, 256, 0, stream>>>(bhist, csum);
  scan_c2<<<TSTEPS, 512, 0, stream>>>(csum, cbase);
  scan_c3<<<TSTEPS * NCHK2, 512, 0, stream>>>(bhist, cbase, bscan);
  coarse_scatter<<<dim3(NBLK, TSTEPS), 512, 0, stream>>>(edges, weights, bscan, tmp);
  fine_sort<<<dim3(COARSE, TSTEPS), 512, 0, stream>>>(bscan, tmp, csr, offs);

  // ---- weight/bias preprocessing ----
  fuse_w<<<TSTEPS * HDIM, H3, 0, stream>>>(gW2, Wx, Wf32);
  fuse_b<<<TSTEPS, H3, 0, stream>>>(gb2, Wx, bx, bfb);
  pack_wcomb<<<TSTEPS * 512, 256, 0, stream>>>(Wf32, Wh, Wcombt);
  pack_bcomb<<<TSTEPS, 512, 0, stream>>>(bfb, bh_in, bcomb);

  static_encode8<<<(NNODES + 7) / 8, 64, 0, stream>>>(
      static_dense, static_sparse, s_emb, Ws, bs, Waw, baw, acch, sden, mxv);

  const int GRUB = (NNODES + 63) / 64;
  for (int t = 0; t < TSTEPS; ++t) {
    const int* off_t = offs + (size_t)t * (NKEY + 1);
    const unsigned int* csr_t = csr + (size_t)t * NEDGES;
    _Float16* hcur = (t & 1) ? hB : hA;
    const _Float16* hprev = (t == 0) ? nullptr : ((t & 1) ? hA : hB);

    dynx_gather_h<<<(NNODES * 8 + 255) / 256, 256, 0, stream>>>(
        dyn_dense + (size_t)t * N * DDIM, dyn_sparse + (size_t)t * N * 2, d_emb, dynx);

    gcn1_fused<<<(NNODES + 31) / 32, 256, 0, stream>>>(
        off_t, csr_t, dynx, gW1 + (size_t)t * G0DIM * HDIM, gb1 + (size_t)t * HDIM, h1h);

    gru_mfma<<<GRUB, 512, 0, stream>>>(
        off_t, csr_t, h1h, hprev, Wcombt + (size_t)t * 512 * 256, bcomb + t * 512,
        Waw, baw, hcur, acch, out, sden, mxv, t == TSTEPS - 1 ? 1 : 0);
  }
}